// Round 12
// baseline (335.529 us; speedup 1.0000x reference)
//
#include <hip/hip_runtime.h>
#include <hip/hip_bf16.h>

#define NN 100000
#define NE 1600000
#define DIN 8
#define DH 32
#define NACT 3
#define NBLK 391          // ceil(NN/256)
#define PADN (NBLK * 256)
#define NRANGE 12500      // NN / 8
#define PA 200            // partition blocks
#define ECA (NE / PA)     // 8000 edges per partition chunk (mult of 4)
#define CAPB 204800       // per-bucket capacity (mean 200K, +11 sigma)
#define KB 125            // blocks per bucket for count/fill
#define LG32 (NN / 32)    // 3125 blocks x 32 nodes (exact)

typedef __hip_bfloat16 bf;
typedef unsigned short u16;
typedef __attribute__((ext_vector_type(8))) short bf16x8;
typedef __attribute__((ext_vector_type(4))) float f32x4;

__device__ __forceinline__ float bflo(unsigned u) { return __uint_as_float(u << 16); }
__device__ __forceinline__ float bfhi(unsigned u) { return __uint_as_float(u & 0xffff0000u); }
__device__ __forceinline__ unsigned pk2(float lo, float hi) {
    union { bf b; unsigned short u; } cl, ch;
    cl.b = __float2bfloat16(lo); ch.b = __float2bfloat16(hi);
    return (unsigned)cl.u | ((unsigned)ch.u << 16);
}

// ---------------- weight prep (bf16 transposed panels) ----------------
__launch_bounds__(256)
__global__ void prep_weights(const float* __restrict__ Wl1, const float* __restrict__ Wr1,
                             const float* __restrict__ Wl2, const float* __restrict__ Wr2,
                             const float* __restrict__ Wl3, const float* __restrict__ Wr3,
                             const float* __restrict__ Wh1,
                             u16* __restrict__ B1t, u16* __restrict__ B2t,
                             u16* __restrict__ B3t, u16* __restrict__ Bh1t) {
    int tid = threadIdx.x;
    for (int idx = tid; idx < 1024; idx += 256) {
        int j = idx >> 5, k = idx & 31;
        float v = (k < 8) ? Wl1[k * DH + j] : ((k < 16) ? Wr1[(k - 8) * DH + j] : 0.0f);
        reinterpret_cast<bf*>(B1t)[j * 32 + k] = __float2bfloat16(v);
    }
    for (int idx = tid; idx < 2048; idx += 256) {
        int j = idx >> 6, k = idx & 63;
        float v = (k < 32) ? Wl2[k * DH + j] : Wr2[(k - 32) * DH + j];
        reinterpret_cast<bf*>(B2t)[j * 64 + k] = __float2bfloat16(v);
    }
    for (int idx = tid; idx < 2048; idx += 256) {
        int j = idx >> 6, k = idx & 63;
        float v = (k < 32) ? Wl3[k * DH + j] : Wr3[(k - 32) * DH + j];
        reinterpret_cast<bf*>(B3t)[j * 64 + k] = __float2bfloat16(v);
    }
    for (int idx = tid; idx < 1024; idx += 256) {
        int j = idx >> 5, k = idx & 31;
        reinterpret_cast<bf*>(Bh1t)[j * 32 + k] = __float2bfloat16(Wh1[k * DH + j]);
    }
}

// ---------------- phase A: 8-way radix partition of edges by dst range ----------------
// packed entry: (src << 14) | (dst - range*NRANGE);  src < 2^17, dlocal < 2^14
__launch_bounds__(256)
__global__ void partition_edges(const int* __restrict__ src, const int* __restrict__ dst,
                                int* __restrict__ bucket_cnt, unsigned* __restrict__ ebuf) {
    __shared__ int lcnt[8];
    __shared__ int lbase[8];
    int tid = threadIdx.x;
    if (tid < 8) lcnt[tid] = 0;
    __syncthreads();

    int e0 = blockIdx.x * ECA;
    // pass 1: count
    for (int e = e0 + tid * 4; e < e0 + ECA; e += 1024) {
        int4 d4 = *reinterpret_cast<const int4*>(&dst[e]);
        atomicAdd(&lcnt[(unsigned)d4.x / NRANGE], 1);
        atomicAdd(&lcnt[(unsigned)d4.y / NRANGE], 1);
        atomicAdd(&lcnt[(unsigned)d4.z / NRANGE], 1);
        atomicAdd(&lcnt[(unsigned)d4.w / NRANGE], 1);
    }
    __syncthreads();
    if (tid < 8) {
        lbase[tid] = atomicAdd(&bucket_cnt[tid], lcnt[tid]);
        lcnt[tid] = 0;
    }
    __syncthreads();
    // pass 2: scatter (chunk re-read is L2-hot)
    for (int e = e0 + tid * 4; e < e0 + ECA; e += 1024) {
        int4 d4 = *reinterpret_cast<const int4*>(&dst[e]);
        int4 s4 = *reinterpret_cast<const int4*>(&src[e]);
        int r, pos;
        r = (unsigned)d4.x / NRANGE; pos = lbase[r] + atomicAdd(&lcnt[r], 1);
        ebuf[r * CAPB + pos] = ((unsigned)s4.x << 14) | (unsigned)(d4.x - r * NRANGE);
        r = (unsigned)d4.y / NRANGE; pos = lbase[r] + atomicAdd(&lcnt[r], 1);
        ebuf[r * CAPB + pos] = ((unsigned)s4.y << 14) | (unsigned)(d4.y - r * NRANGE);
        r = (unsigned)d4.z / NRANGE; pos = lbase[r] + atomicAdd(&lcnt[r], 1);
        ebuf[r * CAPB + pos] = ((unsigned)s4.z << 14) | (unsigned)(d4.z - r * NRANGE);
        r = (unsigned)d4.w / NRANGE; pos = lbase[r] + atomicAdd(&lcnt[r], 1);
        ebuf[r * CAPB + pos] = ((unsigned)s4.w << 14) | (unsigned)(d4.w - r * NRANGE);
    }
}

// ---------------- phase B: degree count, XCD-local ----------------
__launch_bounds__(256)
__global__ void count_deg_b(const int* __restrict__ bucket_cnt,
                            const unsigned* __restrict__ ebuf, int* __restrict__ degI) {
    int g = blockIdx.x & 7;
    int blk = blockIdx.x >> 3;
    int n = bucket_cnt[g];
    int lo = g * NRANGE;
    const unsigned* eb = ebuf + g * CAPB;
    for (int i = blk * 256 + (int)threadIdx.x; i < n; i += KB * 256) {
        unsigned v = eb[i];
        atomicAdd(&degI[lo + (v & 16383u)], 1);
    }
}

// ---------------- scan A/B/C ----------------
__launch_bounds__(256)
__global__ void scanA(const int* __restrict__ degI, int* __restrict__ incl,
                      int* __restrict__ bsum) {
    __shared__ int s[256];
    int i = blockIdx.x * 256 + threadIdx.x;
    int v = (i < NN) ? degI[i] : 0;
    s[threadIdx.x] = v;
    __syncthreads();
#pragma unroll
    for (int off = 1; off < 256; off <<= 1) {
        int t = (threadIdx.x >= off) ? s[threadIdx.x - off] : 0;
        __syncthreads();
        s[threadIdx.x] += t;
        __syncthreads();
    }
    incl[i] = s[threadIdx.x];
    if (threadIdx.x == 255) bsum[blockIdx.x] = s[255];
}

__launch_bounds__(512)
__global__ void scanB(int* __restrict__ bsum) {
    __shared__ int s[512];
    int tid = threadIdx.x;
    int v = (tid < NBLK) ? bsum[tid] : 0;
    s[tid] = v;
    __syncthreads();
#pragma unroll
    for (int off = 1; off < 512; off <<= 1) {
        int t = (tid >= off) ? s[tid - off] : 0;
        __syncthreads();
        s[tid] += t;
        __syncthreads();
    }
    if (tid < NBLK) bsum[tid] = s[tid] - v;
}

__launch_bounds__(256)
__global__ void scanC(const int* __restrict__ incl, const int* __restrict__ degI,
                      const int* __restrict__ bsum, int* __restrict__ start,
                      int* __restrict__ cursor) {
    int i = blockIdx.x * 256 + threadIdx.x;
    if (i < NN) {
        int st = incl[i] - degI[i] + bsum[blockIdx.x];
        start[i] = st;
        cursor[i] = st;
    }
}

// ---------------- phase B: CSR fill, XCD-local ----------------
__launch_bounds__(256)
__global__ void fill_csr_b(const int* __restrict__ bucket_cnt,
                           const unsigned* __restrict__ ebuf,
                           int* __restrict__ cursor, int* __restrict__ adj) {
    int g = blockIdx.x & 7;
    int blk = blockIdx.x >> 3;
    int n = bucket_cnt[g];
    int lo = g * NRANGE;
    const unsigned* eb = ebuf + g * CAPB;
    for (int i = blk * 256 + (int)threadIdx.x; i < n; i += KB * 256) {
        unsigned v = eb[i];
        int d = lo + (int)(v & 16383u);
        adj[atomicAdd(&cursor[d], 1)] = (int)(v >> 14);
    }
}

// ============ layer 1: uniform-shfl gather(d=8,f32) -> A[32][72] -> MFMA ============
__launch_bounds__(128)
__global__ void layer1_mfma(const float* __restrict__ x, const int* __restrict__ degI,
                            const int* __restrict__ start, const int* __restrict__ adj,
                            const u16* __restrict__ Bt, const float* __restrict__ blv,
                            bf* __restrict__ hout) {
    __shared__ __align__(16) short sA[32 * 72];
    int tid = threadIdx.x;
    int base = blockIdx.x * 32;

    {   // zero pad k=16..31 region
        int row = tid >> 2, part = tid & 3;
        *reinterpret_cast<uint2*>(&sA[row * 72 + 16 + part * 4]) = make_uint2(0u, 0u);
    }

    int g = tid >> 5, t = tid & 31;
    int nb = t >> 1, q = t & 1;
    int nbase = base + g * 8;
    int dgv = 0, stv = 0;
    if (t < 8) { dgv = degI[nbase + t]; stv = start[nbase + t]; }

#pragma unroll 4
    for (int i = 0; i < 8; ++i) {
        int dg  = __shfl(dgv, i, 32);
        int row = __shfl(stv, i, 32);
        int node = nbase + i;
        int idxreg = (t < dg) ? adj[row + t] : 0;
        float4 xv;
        if (t == 2 || t == 3)
            xv = *reinterpret_cast<const float4*>(&x[node * DIN + (t - 2) * 4]);
        float a[4] = {0.f, 0.f, 0.f, 0.f};
        int lim = min(dg, 32);
        int nit = (lim + 15) >> 4;
        for (int j = 0; j < nit; ++j) {
            int k = nb + j * 16;
            int s = __shfl(idxreg, k, 32);
            float4 v = *reinterpret_cast<const float4*>(&x[s * DIN + q * 4]);
            if (k < lim) { a[0] += v.x; a[1] += v.y; a[2] += v.z; a[3] += v.w; }
        }
        for (int k = 32 + nb; k < dg; k += 16) {
            int s = adj[row + k];
            float4 v = *reinterpret_cast<const float4*>(&x[s * DIN + q * 4]);
            a[0] += v.x; a[1] += v.y; a[2] += v.z; a[3] += v.w;
        }
#pragma unroll
        for (int m = 0; m < 4; ++m) {
            a[m] += __shfl_xor(a[m], 2);
            a[m] += __shfl_xor(a[m], 4);
            a[m] += __shfl_xor(a[m], 8);
            a[m] += __shfl_xor(a[m], 16);
        }
        int nrow = g * 8 + i;
        if (t < 2) {
            float inv = 1.0f / fmaxf((float)dg, 1.0f);
            uint2 mm;
            mm.x = pk2(a[0] * inv, a[1] * inv);
            mm.y = pk2(a[2] * inv, a[3] * inv);
            *reinterpret_cast<uint2*>(&sA[nrow * 72 + t * 4]) = mm;
        } else if (t < 4) {
            uint2 xm;
            xm.x = pk2(xv.x, xv.y);
            xm.y = pk2(xv.z, xv.w);
            *reinterpret_cast<uint2*>(&sA[nrow * 72 + 8 + (t - 2) * 4]) = xm;
        }
    }
    __syncthreads();

    int wid = tid >> 6, lane = tid & 63;
    int r16 = lane & 15, k8 = (lane >> 4) * 8;
    bf16x8 av = *reinterpret_cast<const bf16x8*>(&sA[(wid * 16 + r16) * 72 + k8]);
    bf16x8 b0 = *reinterpret_cast<const bf16x8*>(&Bt[r16 * 32 + k8]);
    bf16x8 b1 = *reinterpret_cast<const bf16x8*>(&Bt[(16 + r16) * 32 + k8]);
    f32x4 acc0 = {0.f, 0.f, 0.f, 0.f}, acc1 = {0.f, 0.f, 0.f, 0.f};
    acc0 = __builtin_amdgcn_mfma_f32_16x16x32_bf16(av, b0, acc0, 0, 0, 0);
    acc1 = __builtin_amdgcn_mfma_f32_16x16x32_bf16(av, b1, acc1, 0, 0, 0);
    float bias0 = blv[r16], bias1 = blv[16 + r16];
    int rbase = base + wid * 16 + (lane >> 4) * 4;
#pragma unroll
    for (int reg = 0; reg < 4; ++reg) {
        int node = rbase + reg;
        hout[node * DH + r16]      = __float2bfloat16(fmaxf(acc0[reg] + bias0, 0.f));
        hout[node * DH + 16 + r16] = __float2bfloat16(fmaxf(acc1[reg] + bias1, 0.f));
    }
}

// ============ shared gather for d=32 bf16 panels (uniform shfl loop) ============
__device__ __forceinline__ void gather32(const bf* __restrict__ hin,
                                         const int* __restrict__ degI,
                                         const int* __restrict__ start,
                                         const int* __restrict__ adj,
                                         short* sA, int base, int tid) {
    int g = tid >> 5, t = tid & 31;
    int nb = t >> 2, q = t & 3;
    int nbase = base + g * 8;
    int dgv = 0, stv = 0;
    if (t < 8) { dgv = degI[nbase + t]; stv = start[nbase + t]; }

#pragma unroll 4
    for (int i = 0; i < 8; ++i) {
        int dg  = __shfl(dgv, i, 32);
        int row = __shfl(stv, i, 32);
        int node = nbase + i;
        int idxreg = (t < dg) ? adj[row + t] : 0;
        uint4 xru;
        if ((t & 28) == 4)
            xru = *reinterpret_cast<const uint4*>(&hin[node * DH + (t - 4) * 8]);
        float a[8] = {0.f, 0.f, 0.f, 0.f, 0.f, 0.f, 0.f, 0.f};
        int lim = min(dg, 32);
        int nit = (lim + 7) >> 3;
        for (int j = 0; j < nit; ++j) {
            int k = nb + j * 8;
            int s = __shfl(idxreg, k, 32);
            uint4 u = *reinterpret_cast<const uint4*>(&hin[s * DH + q * 8]);
            if (k < lim) {
                a[0] += bflo(u.x); a[1] += bfhi(u.x);
                a[2] += bflo(u.y); a[3] += bfhi(u.y);
                a[4] += bflo(u.z); a[5] += bfhi(u.z);
                a[6] += bflo(u.w); a[7] += bfhi(u.w);
            }
        }
        for (int k = 32 + nb; k < dg; k += 8) {
            int s = adj[row + k];
            uint4 u = *reinterpret_cast<const uint4*>(&hin[s * DH + q * 8]);
            a[0] += bflo(u.x); a[1] += bfhi(u.x);
            a[2] += bflo(u.y); a[3] += bfhi(u.y);
            a[4] += bflo(u.z); a[5] += bfhi(u.z);
            a[6] += bflo(u.w); a[7] += bfhi(u.w);
        }
#pragma unroll
        for (int m = 0; m < 8; ++m) {
            a[m] += __shfl_xor(a[m], 4);
            a[m] += __shfl_xor(a[m], 8);
            a[m] += __shfl_xor(a[m], 16);
        }
        int nrow = g * 8 + i;
        if (t < 4) {
            float inv = 1.0f / fmaxf((float)dg, 1.0f);
            uint4 mm;
            mm.x = pk2(a[0] * inv, a[1] * inv);
            mm.y = pk2(a[2] * inv, a[3] * inv);
            mm.z = pk2(a[4] * inv, a[5] * inv);
            mm.w = pk2(a[6] * inv, a[7] * inv);
            *reinterpret_cast<uint4*>(&sA[nrow * 72 + t * 8]) = mm;
        } else if (t < 8) {
            *reinterpret_cast<uint4*>(&sA[nrow * 72 + 32 + (t - 4) * 8]) = xru;
        }
    }
}

// ============ layer 2 ============
__launch_bounds__(128)
__global__ void layer2_mfma(const bf* __restrict__ hin, const int* __restrict__ degI,
                            const int* __restrict__ start, const int* __restrict__ adj,
                            const u16* __restrict__ Bt, const float* __restrict__ blv,
                            bf* __restrict__ hout) {
    __shared__ __align__(16) short sA[32 * 72];
    int tid = threadIdx.x;
    int base = blockIdx.x * 32;

    gather32(hin, degI, start, adj, sA, base, tid);
    __syncthreads();

    int wid = tid >> 6, lane = tid & 63;
    int r16 = lane & 15, k8 = (lane >> 4) * 8;
    const short* ap = &sA[(wid * 16 + r16) * 72];
    bf16x8 av0 = *reinterpret_cast<const bf16x8*>(&ap[k8]);
    bf16x8 av1 = *reinterpret_cast<const bf16x8*>(&ap[32 + k8]);
    const u16* b0p = &Bt[r16 * 64];
    const u16* b1p = &Bt[(16 + r16) * 64];
    bf16x8 b00 = *reinterpret_cast<const bf16x8*>(&b0p[k8]);
    bf16x8 b01 = *reinterpret_cast<const bf16x8*>(&b0p[32 + k8]);
    bf16x8 b10 = *reinterpret_cast<const bf16x8*>(&b1p[k8]);
    bf16x8 b11 = *reinterpret_cast<const bf16x8*>(&b1p[32 + k8]);
    f32x4 acc0 = {0.f, 0.f, 0.f, 0.f}, acc1 = {0.f, 0.f, 0.f, 0.f};
    acc0 = __builtin_amdgcn_mfma_f32_16x16x32_bf16(av0, b00, acc0, 0, 0, 0);
    acc0 = __builtin_amdgcn_mfma_f32_16x16x32_bf16(av1, b01, acc0, 0, 0, 0);
    acc1 = __builtin_amdgcn_mfma_f32_16x16x32_bf16(av0, b10, acc1, 0, 0, 0);
    acc1 = __builtin_amdgcn_mfma_f32_16x16x32_bf16(av1, b11, acc1, 0, 0, 0);
    float bias0 = blv[r16], bias1 = blv[16 + r16];
    int rbase = base + wid * 16 + (lane >> 4) * 4;
#pragma unroll
    for (int reg = 0; reg < 4; ++reg) {
        int node = rbase + reg;
        hout[node * DH + r16]      = __float2bfloat16(fmaxf(acc0[reg] + bias0, 0.f));
        hout[node * DH + 16 + r16] = __float2bfloat16(fmaxf(acc1[reg] + bias1, 0.f));
    }
}

// ============ layer 3 + head (LDS overlaid: sA -> h3 -> hmid) ============
__launch_bounds__(128)
__global__ void layer3_mfma(const bf* __restrict__ hin, const int* __restrict__ degI,
                            const int* __restrict__ start, const int* __restrict__ adj,
                            const u16* __restrict__ B3t, const float* __restrict__ bl3,
                            const u16* __restrict__ Bh1t, const float* __restrict__ bh1,
                            const float* __restrict__ Wh2, const float* __restrict__ bh2,
                            float* __restrict__ out) {
    __shared__ __align__(16) short sA[32 * 72];
    __shared__ float sW2[NACT * DH];
    int tid = threadIdx.x;
    int base = blockIdx.x * 32;

    if (tid < NACT * DH) {
        int a = tid >> 5, k = tid & 31;
        sW2[a * DH + k] = Wh2[k * NACT + a];
    }

    gather32(hin, degI, start, adj, sA, base, tid);
    __syncthreads();

    int wid = tid >> 6, lane = tid & 63;
    int r16 = lane & 15, k8 = (lane >> 4) * 8;
    int rloc = wid * 16 + (lane >> 4) * 4;

    // stage 1: SAGE conv
    f32x4 acc0 = {0.f, 0.f, 0.f, 0.f}, acc1 = {0.f, 0.f, 0.f, 0.f};
    {
        const short* ap = &sA[(wid * 16 + r16) * 72];
        bf16x8 av0 = *reinterpret_cast<const bf16x8*>(&ap[k8]);
        bf16x8 av1 = *reinterpret_cast<const bf16x8*>(&ap[32 + k8]);
        const u16* b0p = &B3t[r16 * 64];
        const u16* b1p = &B3t[(16 + r16) * 64];
        bf16x8 b00 = *reinterpret_cast<const bf16x8*>(&b0p[k8]);
        bf16x8 b01 = *reinterpret_cast<const bf16x8*>(&b0p[32 + k8]);
        bf16x8 b10 = *reinterpret_cast<const bf16x8*>(&b1p[k8]);
        bf16x8 b11 = *reinterpret_cast<const bf16x8*>(&b1p[32 + k8]);
        acc0 = __builtin_amdgcn_mfma_f32_16x16x32_bf16(av0, b00, acc0, 0, 0, 0);
        acc0 = __builtin_amdgcn_mfma_f32_16x16x32_bf16(av1, b01, acc0, 0, 0, 0);
        acc1 = __builtin_amdgcn_mfma_f32_16x16x32_bf16(av0, b10, acc1, 0, 0, 0);
        acc1 = __builtin_amdgcn_mfma_f32_16x16x32_bf16(av1, b11, acc1, 0, 0, 0);
    }
    __syncthreads();

    bf* h3b = reinterpret_cast<bf*>(sA);   // overlay: [32][40] bf16
    {
        float bias0 = bl3[r16], bias1 = bl3[16 + r16];
#pragma unroll
        for (int reg = 0; reg < 4; ++reg) {
            int rr = rloc + reg;
            h3b[rr * 40 + r16]      = __float2bfloat16(fmaxf(acc0[reg] + bias0, 0.f));
            h3b[rr * 40 + 16 + r16] = __float2bfloat16(fmaxf(acc1[reg] + bias1, 0.f));
        }
    }
    __syncthreads();

    // stage 2: hmid = relu(h3 @ Wh1 + bh1)
    f32x4 d0 = {0.f, 0.f, 0.f, 0.f}, d1 = {0.f, 0.f, 0.f, 0.f};
    {
        bf16x8 av = *reinterpret_cast<const bf16x8*>(&h3b[(wid * 16 + r16) * 40 + k8]);
        bf16x8 b0 = *reinterpret_cast<const bf16x8*>(&Bh1t[r16 * 32 + k8]);
        bf16x8 b1 = *reinterpret_cast<const bf16x8*>(&Bh1t[(16 + r16) * 32 + k8]);
        d0 = __builtin_amdgcn_mfma_f32_16x16x32_bf16(av, b0, d0, 0, 0, 0);
        d1 = __builtin_amdgcn_mfma_f32_16x16x32_bf16(av, b1, d1, 0, 0, 0);
    }
    __syncthreads();

    float* shm = reinterpret_cast<float*>(sA);   // overlay: [32][36] f32
    {
        float hb0 = bh1[r16], hb1 = bh1[16 + r16];
#pragma unroll
        for (int reg = 0; reg < 4; ++reg) {
            int rr = rloc + reg;
            shm[rr * 36 + r16]      = fmaxf(d0[reg] + hb0, 0.f);
            shm[rr * 36 + 16 + r16] = fmaxf(d1[reg] + hb1, 0.f);
        }
    }
    __syncthreads();

    // stage 3: out = hmid @ Wh2 + bh2
    {
        int m = tid >> 2, a = tid & 3;
        if (a < NACT) {
            float o = bh2[a];
            const float* hp = &shm[m * 36];
            const float* wp = &sW2[a * DH];
#pragma unroll
            for (int k = 0; k < DH; k += 4) {
                f32x4 hv = *reinterpret_cast<const f32x4*>(&hp[k]);
                f32x4 wv = *reinterpret_cast<const f32x4*>(&wp[k]);
                o += hv.x * wv.x + hv.y * wv.y + hv.z * wv.z + hv.w * wv.w;
            }
            out[(base + m) * NACT + a] = o;
        }
    }
}

extern "C" void kernel_launch(void* const* d_in, const int* in_sizes, int n_in,
                              void* d_out, int out_size, void* d_ws, size_t ws_size,
                              hipStream_t stream) {
    const float* x   = (const float*)d_in[0];
    const int*   ei  = (const int*)d_in[1];
    const int*   src = ei;
    const int*   dst = ei + NE;
    const float* Wl1 = (const float*)d_in[2];
    const float* bl1 = (const float*)d_in[3];
    const float* Wr1 = (const float*)d_in[4];
    const float* Wl2 = (const float*)d_in[5];
    const float* bl2 = (const float*)d_in[6];
    const float* Wr2 = (const float*)d_in[7];
    const float* Wl3 = (const float*)d_in[8];
    const float* bl3 = (const float*)d_in[9];
    const float* Wr3 = (const float*)d_in[10];
    const float* Wh1 = (const float*)d_in[11];
    const float* bh1 = (const float*)d_in[12];
    const float* Wh2 = (const float*)d_in[13];
    const float* bh2 = (const float*)d_in[14];
    float* out = (float*)d_out;

    int* degI     = (int*)d_ws;              // NN
    int* bucket   = degI + NN;               // 8
    int* startP   = bucket + 8;              // NN
    int* cursor   = startP + NN;             // NN
    int* bsum     = cursor + NN;             // 512
    int* incl     = bsum + 512;              // PADN
    int* adj      = incl + PADN;             // NE
    unsigned* ebuf = (unsigned*)(adj + NE);  // 8*CAPB
    u16* B1t      = (u16*)(ebuf + 8 * CAPB); // 1024
    u16* B2t      = B1t + 1024;              // 2048
    u16* B3t      = B2t + 2048;              // 2048
    u16* Bh1t     = B3t + 2048;              // 1024
    bf*  hA       = (bf*)(Bh1t + 1024);      // DH*NN
    bf*  hB       = hA + DH * NN;            // DH*NN

    // zero degI + bucket counters in one memset (they're adjacent)
    hipMemsetAsync(degI, 0, (NN + 8) * sizeof(int), stream);

    prep_weights<<<1, 256, 0, stream>>>(Wl1, Wr1, Wl2, Wr2, Wl3, Wr3, Wh1,
                                        B1t, B2t, B3t, Bh1t);

    // ---- build CSR: radix partition -> XCD-local count/scan/fill ----
    partition_edges<<<PA, 256, 0, stream>>>(src, dst, bucket, ebuf);
    count_deg_b<<<KB * 8, 256, 0, stream>>>(bucket, ebuf, degI);
    scanA<<<NBLK, 256, 0, stream>>>(degI, incl, bsum);
    scanB<<<1, 512, 0, stream>>>(bsum);
    scanC<<<NBLK, 256, 0, stream>>>(incl, degI, bsum, startP, cursor);
    fill_csr_b<<<KB * 8, 256, 0, stream>>>(bucket, ebuf, cursor, adj);

    // ---- layers ----
    layer1_mfma<<<LG32, 128, 0, stream>>>(x, degI, startP, adj, B1t, bl1, hA);
    layer2_mfma<<<LG32, 128, 0, stream>>>(hA, degI, startP, adj, B2t, bl2, hB);
    layer3_mfma<<<LG32, 128, 0, stream>>>(hB, degI, startP, adj, B3t, bl3,
                                          Bh1t, bh1, Wh2, bh2, out);
}

// Round 13
// 228.007 us; speedup vs baseline: 1.4716x; 1.4716x over previous
//
#include <hip/hip_runtime.h>
#include <hip/hip_bf16.h>

#define NN 100000
#define NE 1600000
#define DIN 8
#define DH 32
#define NACT 3
#define NBLK 391          // ceil(NN/256)
#define PADN (NBLK * 256)
#define BKN 128           // nodes per bucket
#define NBKT 782          // ceil(NN/BKN)
#define CAPB 3072         // per-bucket capacity (mean 2048, +16 sigma)
#define PA 128            // partition blocks
#define ECA (NE / PA)     // 12500 edges per chunk, mult of 4
#define LG32 (NN / 32)    // 3125 blocks x 32 nodes (exact)

typedef __hip_bfloat16 bf;
typedef unsigned short u16;
typedef __attribute__((ext_vector_type(8))) short bf16x8;
typedef __attribute__((ext_vector_type(4))) float f32x4;

__device__ __forceinline__ float bflo(unsigned u) { return __uint_as_float(u << 16); }
__device__ __forceinline__ float bfhi(unsigned u) { return __uint_as_float(u & 0xffff0000u); }
__device__ __forceinline__ unsigned pk2(float lo, float hi) {
    union { bf b; unsigned short u; } cl, ch;
    cl.b = __float2bfloat16(lo); ch.b = __float2bfloat16(hi);
    return (unsigned)cl.u | ((unsigned)ch.u << 16);
}

// ---------------- weight prep (bf16 transposed panels) ----------------
__launch_bounds__(256)
__global__ void prep_weights(const float* __restrict__ Wl1, const float* __restrict__ Wr1,
                             const float* __restrict__ Wl2, const float* __restrict__ Wr2,
                             const float* __restrict__ Wl3, const float* __restrict__ Wr3,
                             const float* __restrict__ Wh1,
                             u16* __restrict__ B1t, u16* __restrict__ B2t,
                             u16* __restrict__ B3t, u16* __restrict__ Bh1t) {
    int tid = threadIdx.x;
    for (int idx = tid; idx < 1024; idx += 256) {
        int j = idx >> 5, k = idx & 31;
        float v = (k < 8) ? Wl1[k * DH + j] : ((k < 16) ? Wr1[(k - 8) * DH + j] : 0.0f);
        reinterpret_cast<bf*>(B1t)[j * 32 + k] = __float2bfloat16(v);
    }
    for (int idx = tid; idx < 2048; idx += 256) {
        int j = idx >> 6, k = idx & 63;
        float v = (k < 32) ? Wl2[k * DH + j] : Wr2[(k - 32) * DH + j];
        reinterpret_cast<bf*>(B2t)[j * 64 + k] = __float2bfloat16(v);
    }
    for (int idx = tid; idx < 2048; idx += 256) {
        int j = idx >> 6, k = idx & 63;
        float v = (k < 32) ? Wl3[k * DH + j] : Wr3[(k - 32) * DH + j];
        reinterpret_cast<bf*>(B3t)[j * 64 + k] = __float2bfloat16(v);
    }
    for (int idx = tid; idx < 1024; idx += 256) {
        int j = idx >> 5, k = idx & 31;
        reinterpret_cast<bf*>(Bh1t)[j * 32 + k] = __float2bfloat16(Wh1[k * DH + j]);
    }
}

// ---------------- phase A: 782-way radix partition by dst/128 ----------------
// packed entry: (src << 7) | (dst & 127);  src < 2^17
__launch_bounds__(256)
__global__ void partition_edges(const int* __restrict__ src, const int* __restrict__ dst,
                                int* __restrict__ bucket_cnt, unsigned* __restrict__ ebuf) {
    __shared__ int lcnt[NBKT];
    __shared__ int lbase[NBKT];
    int tid = threadIdx.x;
    for (int r = tid; r < NBKT; r += 256) lcnt[r] = 0;
    __syncthreads();

    int e0 = blockIdx.x * ECA;
    // pass 1: count
    for (int e = e0 + tid * 4; e < e0 + ECA; e += 1024) {
        int4 d4 = *reinterpret_cast<const int4*>(&dst[e]);
        atomicAdd(&lcnt[(unsigned)d4.x >> 7], 1);
        atomicAdd(&lcnt[(unsigned)d4.y >> 7], 1);
        atomicAdd(&lcnt[(unsigned)d4.z >> 7], 1);
        atomicAdd(&lcnt[(unsigned)d4.w >> 7], 1);
    }
    __syncthreads();
    // reserve contiguous runs per bucket (only global atomics in the build)
    for (int r = tid; r < NBKT; r += 256) {
        lbase[r] = atomicAdd(&bucket_cnt[r], lcnt[r]);
        lcnt[r] = 0;
    }
    __syncthreads();
    // pass 2: scatter (chunk re-read is L2-hot); runs are contiguous per block
    for (int e = e0 + tid * 4; e < e0 + ECA; e += 1024) {
        int4 d4 = *reinterpret_cast<const int4*>(&dst[e]);
        int4 s4 = *reinterpret_cast<const int4*>(&src[e]);
        int r, p;
        r = (unsigned)d4.x >> 7; p = lbase[r] + atomicAdd(&lcnt[r], 1);
        if (p < CAPB) ebuf[r * CAPB + p] = ((unsigned)s4.x << 7) | ((unsigned)d4.x & 127u);
        r = (unsigned)d4.y >> 7; p = lbase[r] + atomicAdd(&lcnt[r], 1);
        if (p < CAPB) ebuf[r * CAPB + p] = ((unsigned)s4.y << 7) | ((unsigned)d4.y & 127u);
        r = (unsigned)d4.z >> 7; p = lbase[r] + atomicAdd(&lcnt[r], 1);
        if (p < CAPB) ebuf[r * CAPB + p] = ((unsigned)s4.z << 7) | ((unsigned)d4.z & 127u);
        r = (unsigned)d4.w >> 7; p = lbase[r] + atomicAdd(&lcnt[r], 1);
        if (p < CAPB) ebuf[r * CAPB + p] = ((unsigned)s4.w << 7) | ((unsigned)d4.w & 127u);
    }
}

// ---------------- per-bucket degree count: LDS histogram, no global atomics ----------------
__launch_bounds__(256)
__global__ void count_local(const int* __restrict__ bucket_cnt,
                            const unsigned* __restrict__ ebuf, int* __restrict__ degI) {
    __shared__ int cnt[BKN];
    int tid = threadIdx.x;
    int r = blockIdx.x;
    if (tid < BKN) cnt[tid] = 0;
    __syncthreads();
    int n = min(bucket_cnt[r], CAPB);
    const unsigned* eb = ebuf + r * CAPB;
    for (int i = tid; i < n; i += 256)
        atomicAdd(&cnt[eb[i] & 127u], 1);
    __syncthreads();
    int node = r * BKN + tid;
    if (tid < BKN && node < NN) degI[node] = cnt[tid];
}

// ---------------- scan A/B/C ----------------
__launch_bounds__(256)
__global__ void scanA(const int* __restrict__ degI, int* __restrict__ incl,
                      int* __restrict__ bsum) {
    __shared__ int s[256];
    int i = blockIdx.x * 256 + threadIdx.x;
    int v = (i < NN) ? degI[i] : 0;
    s[threadIdx.x] = v;
    __syncthreads();
#pragma unroll
    for (int off = 1; off < 256; off <<= 1) {
        int t = (threadIdx.x >= off) ? s[threadIdx.x - off] : 0;
        __syncthreads();
        s[threadIdx.x] += t;
        __syncthreads();
    }
    incl[i] = s[threadIdx.x];
    if (threadIdx.x == 255) bsum[blockIdx.x] = s[255];
}

__launch_bounds__(512)
__global__ void scanB(int* __restrict__ bsum) {
    __shared__ int s[512];
    int tid = threadIdx.x;
    int v = (tid < NBLK) ? bsum[tid] : 0;
    s[tid] = v;
    __syncthreads();
#pragma unroll
    for (int off = 1; off < 512; off <<= 1) {
        int t = (tid >= off) ? s[tid - off] : 0;
        __syncthreads();
        s[tid] += t;
        __syncthreads();
    }
    if (tid < NBLK) bsum[tid] = s[tid] - v;
}

__launch_bounds__(256)
__global__ void scanC(const int* __restrict__ incl, const int* __restrict__ degI,
                      const int* __restrict__ bsum, int* __restrict__ start) {
    int i = blockIdx.x * 256 + threadIdx.x;
    if (i < NN)
        start[i] = incl[i] - degI[i] + bsum[blockIdx.x];
}

// ---------------- per-bucket CSR fill: LDS cursor, block-private adj window ----------------
__launch_bounds__(256)
__global__ void fill_local(const int* __restrict__ bucket_cnt,
                           const unsigned* __restrict__ ebuf,
                           const int* __restrict__ start, int* __restrict__ adj) {
    __shared__ int lcur[BKN];
    __shared__ int sstart[BKN];
    int tid = threadIdx.x;
    int r = blockIdx.x;
    if (tid < BKN) {
        lcur[tid] = 0;
        int node = r * BKN + tid;
        sstart[tid] = (node < NN) ? start[node] : 0;
    }
    __syncthreads();
    int n = min(bucket_cnt[r], CAPB);
    const unsigned* eb = ebuf + r * CAPB;
    for (int i = tid; i < n; i += 256) {
        unsigned v = eb[i];
        int d = v & 127u;
        int pos = atomicAdd(&lcur[d], 1);   // LDS atomic: per-CU, fast
        adj[sstart[d] + pos] = (int)(v >> 7);
    }
}

// ============ layer 1: uniform-shfl gather(d=8,f32) -> A[32][72] -> MFMA ============
__launch_bounds__(128)
__global__ void layer1_mfma(const float* __restrict__ x, const int* __restrict__ degI,
                            const int* __restrict__ start, const int* __restrict__ adj,
                            const u16* __restrict__ Bt, const float* __restrict__ blv,
                            bf* __restrict__ hout) {
    __shared__ __align__(16) short sA[32 * 72];
    int tid = threadIdx.x;
    int base = blockIdx.x * 32;

    {   // zero pad k=16..31 region
        int row = tid >> 2, part = tid & 3;
        *reinterpret_cast<uint2*>(&sA[row * 72 + 16 + part * 4]) = make_uint2(0u, 0u);
    }

    int g = tid >> 5, t = tid & 31;
    int nb = t >> 1, q = t & 1;
    int nbase = base + g * 8;
    int dgv = 0, stv = 0;
    if (t < 8) { dgv = degI[nbase + t]; stv = start[nbase + t]; }

#pragma unroll 4
    for (int i = 0; i < 8; ++i) {
        int dg  = __shfl(dgv, i, 32);
        int row = __shfl(stv, i, 32);
        int node = nbase + i;
        int idxreg = (t < dg) ? adj[row + t] : 0;
        float4 xv;
        if (t == 2 || t == 3)
            xv = *reinterpret_cast<const float4*>(&x[node * DIN + (t - 2) * 4]);
        float a[4] = {0.f, 0.f, 0.f, 0.f};
        int lim = min(dg, 32);
        int nit = (lim + 15) >> 4;
        for (int j = 0; j < nit; ++j) {
            int k = nb + j * 16;
            int s = __shfl(idxreg, k, 32);
            float4 v = *reinterpret_cast<const float4*>(&x[s * DIN + q * 4]);
            if (k < lim) { a[0] += v.x; a[1] += v.y; a[2] += v.z; a[3] += v.w; }
        }
        for (int k = 32 + nb; k < dg; k += 16) {
            int s = adj[row + k];
            float4 v = *reinterpret_cast<const float4*>(&x[s * DIN + q * 4]);
            a[0] += v.x; a[1] += v.y; a[2] += v.z; a[3] += v.w;
        }
#pragma unroll
        for (int m = 0; m < 4; ++m) {
            a[m] += __shfl_xor(a[m], 2);
            a[m] += __shfl_xor(a[m], 4);
            a[m] += __shfl_xor(a[m], 8);
            a[m] += __shfl_xor(a[m], 16);
        }
        int nrow = g * 8 + i;
        if (t < 2) {
            float inv = 1.0f / fmaxf((float)dg, 1.0f);
            uint2 mm;
            mm.x = pk2(a[0] * inv, a[1] * inv);
            mm.y = pk2(a[2] * inv, a[3] * inv);
            *reinterpret_cast<uint2*>(&sA[nrow * 72 + t * 4]) = mm;
        } else if (t < 4) {
            uint2 xm;
            xm.x = pk2(xv.x, xv.y);
            xm.y = pk2(xv.z, xv.w);
            *reinterpret_cast<uint2*>(&sA[nrow * 72 + 8 + (t - 2) * 4]) = xm;
        }
    }
    __syncthreads();

    int wid = tid >> 6, lane = tid & 63;
    int r16 = lane & 15, k8 = (lane >> 4) * 8;
    bf16x8 av = *reinterpret_cast<const bf16x8*>(&sA[(wid * 16 + r16) * 72 + k8]);
    bf16x8 b0 = *reinterpret_cast<const bf16x8*>(&Bt[r16 * 32 + k8]);
    bf16x8 b1 = *reinterpret_cast<const bf16x8*>(&Bt[(16 + r16) * 32 + k8]);
    f32x4 acc0 = {0.f, 0.f, 0.f, 0.f}, acc1 = {0.f, 0.f, 0.f, 0.f};
    acc0 = __builtin_amdgcn_mfma_f32_16x16x32_bf16(av, b0, acc0, 0, 0, 0);
    acc1 = __builtin_amdgcn_mfma_f32_16x16x32_bf16(av, b1, acc1, 0, 0, 0);
    float bias0 = blv[r16], bias1 = blv[16 + r16];
    int rbase = base + wid * 16 + (lane >> 4) * 4;
#pragma unroll
    for (int reg = 0; reg < 4; ++reg) {
        int node = rbase + reg;
        hout[node * DH + r16]      = __float2bfloat16(fmaxf(acc0[reg] + bias0, 0.f));
        hout[node * DH + 16 + r16] = __float2bfloat16(fmaxf(acc1[reg] + bias1, 0.f));
    }
}

// ============ shared gather for d=32 bf16 panels (uniform shfl loop) ============
__device__ __forceinline__ void gather32(const bf* __restrict__ hin,
                                         const int* __restrict__ degI,
                                         const int* __restrict__ start,
                                         const int* __restrict__ adj,
                                         short* sA, int base, int tid) {
    int g = tid >> 5, t = tid & 31;
    int nb = t >> 2, q = t & 3;
    int nbase = base + g * 8;
    int dgv = 0, stv = 0;
    if (t < 8) { dgv = degI[nbase + t]; stv = start[nbase + t]; }

#pragma unroll 4
    for (int i = 0; i < 8; ++i) {
        int dg  = __shfl(dgv, i, 32);
        int row = __shfl(stv, i, 32);
        int node = nbase + i;
        int idxreg = (t < dg) ? adj[row + t] : 0;
        uint4 xru;
        if ((t & 28) == 4)
            xru = *reinterpret_cast<const uint4*>(&hin[node * DH + (t - 4) * 8]);
        float a[8] = {0.f, 0.f, 0.f, 0.f, 0.f, 0.f, 0.f, 0.f};
        int lim = min(dg, 32);
        int nit = (lim + 7) >> 3;
        for (int j = 0; j < nit; ++j) {
            int k = nb + j * 8;
            int s = __shfl(idxreg, k, 32);
            uint4 u = *reinterpret_cast<const uint4*>(&hin[s * DH + q * 8]);
            if (k < lim) {
                a[0] += bflo(u.x); a[1] += bfhi(u.x);
                a[2] += bflo(u.y); a[3] += bfhi(u.y);
                a[4] += bflo(u.z); a[5] += bfhi(u.z);
                a[6] += bflo(u.w); a[7] += bfhi(u.w);
            }
        }
        for (int k = 32 + nb; k < dg; k += 8) {
            int s = adj[row + k];
            uint4 u = *reinterpret_cast<const uint4*>(&hin[s * DH + q * 8]);
            a[0] += bflo(u.x); a[1] += bfhi(u.x);
            a[2] += bflo(u.y); a[3] += bfhi(u.y);
            a[4] += bflo(u.z); a[5] += bfhi(u.z);
            a[6] += bflo(u.w); a[7] += bfhi(u.w);
        }
#pragma unroll
        for (int m = 0; m < 8; ++m) {
            a[m] += __shfl_xor(a[m], 4);
            a[m] += __shfl_xor(a[m], 8);
            a[m] += __shfl_xor(a[m], 16);
        }
        int nrow = g * 8 + i;
        if (t < 4) {
            float inv = 1.0f / fmaxf((float)dg, 1.0f);
            uint4 mm;
            mm.x = pk2(a[0] * inv, a[1] * inv);
            mm.y = pk2(a[2] * inv, a[3] * inv);
            mm.z = pk2(a[4] * inv, a[5] * inv);
            mm.w = pk2(a[6] * inv, a[7] * inv);
            *reinterpret_cast<uint4*>(&sA[nrow * 72 + t * 8]) = mm;
        } else if (t < 8) {
            *reinterpret_cast<uint4*>(&sA[nrow * 72 + 32 + (t - 4) * 8]) = xru;
        }
    }
}

// ============ layer 2 ============
__launch_bounds__(128)
__global__ void layer2_mfma(const bf* __restrict__ hin, const int* __restrict__ degI,
                            const int* __restrict__ start, const int* __restrict__ adj,
                            const u16* __restrict__ Bt, const float* __restrict__ blv,
                            bf* __restrict__ hout) {
    __shared__ __align__(16) short sA[32 * 72];
    int tid = threadIdx.x;
    int base = blockIdx.x * 32;

    gather32(hin, degI, start, adj, sA, base, tid);
    __syncthreads();

    int wid = tid >> 6, lane = tid & 63;
    int r16 = lane & 15, k8 = (lane >> 4) * 8;
    const short* ap = &sA[(wid * 16 + r16) * 72];
    bf16x8 av0 = *reinterpret_cast<const bf16x8*>(&ap[k8]);
    bf16x8 av1 = *reinterpret_cast<const bf16x8*>(&ap[32 + k8]);
    const u16* b0p = &Bt[r16 * 64];
    const u16* b1p = &Bt[(16 + r16) * 64];
    bf16x8 b00 = *reinterpret_cast<const bf16x8*>(&b0p[k8]);
    bf16x8 b01 = *reinterpret_cast<const bf16x8*>(&b0p[32 + k8]);
    bf16x8 b10 = *reinterpret_cast<const bf16x8*>(&b1p[k8]);
    bf16x8 b11 = *reinterpret_cast<const bf16x8*>(&b1p[32 + k8]);
    f32x4 acc0 = {0.f, 0.f, 0.f, 0.f}, acc1 = {0.f, 0.f, 0.f, 0.f};
    acc0 = __builtin_amdgcn_mfma_f32_16x16x32_bf16(av0, b00, acc0, 0, 0, 0);
    acc0 = __builtin_amdgcn_mfma_f32_16x16x32_bf16(av1, b01, acc0, 0, 0, 0);
    acc1 = __builtin_amdgcn_mfma_f32_16x16x32_bf16(av0, b10, acc1, 0, 0, 0);
    acc1 = __builtin_amdgcn_mfma_f32_16x16x32_bf16(av1, b11, acc1, 0, 0, 0);
    float bias0 = blv[r16], bias1 = blv[16 + r16];
    int rbase = base + wid * 16 + (lane >> 4) * 4;
#pragma unroll
    for (int reg = 0; reg < 4; ++reg) {
        int node = rbase + reg;
        hout[node * DH + r16]      = __float2bfloat16(fmaxf(acc0[reg] + bias0, 0.f));
        hout[node * DH + 16 + r16] = __float2bfloat16(fmaxf(acc1[reg] + bias1, 0.f));
    }
}

// ============ layer 3 + head (LDS overlaid: sA -> h3 -> hmid) ============
__launch_bounds__(128)
__global__ void layer3_mfma(const bf* __restrict__ hin, const int* __restrict__ degI,
                            const int* __restrict__ start, const int* __restrict__ adj,
                            const u16* __restrict__ B3t, const float* __restrict__ bl3,
                            const u16* __restrict__ Bh1t, const float* __restrict__ bh1,
                            const float* __restrict__ Wh2, const float* __restrict__ bh2,
                            float* __restrict__ out) {
    __shared__ __align__(16) short sA[32 * 72];
    __shared__ float sW2[NACT * DH];
    int tid = threadIdx.x;
    int base = blockIdx.x * 32;

    if (tid < NACT * DH) {
        int a = tid >> 5, k = tid & 31;
        sW2[a * DH + k] = Wh2[k * NACT + a];
    }

    gather32(hin, degI, start, adj, sA, base, tid);
    __syncthreads();

    int wid = tid >> 6, lane = tid & 63;
    int r16 = lane & 15, k8 = (lane >> 4) * 8;
    int rloc = wid * 16 + (lane >> 4) * 4;

    // stage 1: SAGE conv
    f32x4 acc0 = {0.f, 0.f, 0.f, 0.f}, acc1 = {0.f, 0.f, 0.f, 0.f};
    {
        const short* ap = &sA[(wid * 16 + r16) * 72];
        bf16x8 av0 = *reinterpret_cast<const bf16x8*>(&ap[k8]);
        bf16x8 av1 = *reinterpret_cast<const bf16x8*>(&ap[32 + k8]);
        const u16* b0p = &B3t[r16 * 64];
        const u16* b1p = &B3t[(16 + r16) * 64];
        bf16x8 b00 = *reinterpret_cast<const bf16x8*>(&b0p[k8]);
        bf16x8 b01 = *reinterpret_cast<const bf16x8*>(&b0p[32 + k8]);
        bf16x8 b10 = *reinterpret_cast<const bf16x8*>(&b1p[k8]);
        bf16x8 b11 = *reinterpret_cast<const bf16x8*>(&b1p[32 + k8]);
        acc0 = __builtin_amdgcn_mfma_f32_16x16x32_bf16(av0, b00, acc0, 0, 0, 0);
        acc0 = __builtin_amdgcn_mfma_f32_16x16x32_bf16(av1, b01, acc0, 0, 0, 0);
        acc1 = __builtin_amdgcn_mfma_f32_16x16x32_bf16(av0, b10, acc1, 0, 0, 0);
        acc1 = __builtin_amdgcn_mfma_f32_16x16x32_bf16(av1, b11, acc1, 0, 0, 0);
    }
    __syncthreads();

    bf* h3b = reinterpret_cast<bf*>(sA);   // overlay: [32][40] bf16
    {
        float bias0 = bl3[r16], bias1 = bl3[16 + r16];
#pragma unroll
        for (int reg = 0; reg < 4; ++reg) {
            int rr = rloc + reg;
            h3b[rr * 40 + r16]      = __float2bfloat16(fmaxf(acc0[reg] + bias0, 0.f));
            h3b[rr * 40 + 16 + r16] = __float2bfloat16(fmaxf(acc1[reg] + bias1, 0.f));
        }
    }
    __syncthreads();

    // stage 2: hmid = relu(h3 @ Wh1 + bh1)
    f32x4 d0 = {0.f, 0.f, 0.f, 0.f}, d1 = {0.f, 0.f, 0.f, 0.f};
    {
        bf16x8 av = *reinterpret_cast<const bf16x8*>(&h3b[(wid * 16 + r16) * 40 + k8]);
        bf16x8 b0 = *reinterpret_cast<const bf16x8*>(&Bh1t[r16 * 32 + k8]);
        bf16x8 b1 = *reinterpret_cast<const bf16x8*>(&Bh1t[(16 + r16) * 32 + k8]);
        d0 = __builtin_amdgcn_mfma_f32_16x16x32_bf16(av, b0, d0, 0, 0, 0);
        d1 = __builtin_amdgcn_mfma_f32_16x16x32_bf16(av, b1, d1, 0, 0, 0);
    }
    __syncthreads();

    float* shm = reinterpret_cast<float*>(sA);   // overlay: [32][36] f32
    {
        float hb0 = bh1[r16], hb1 = bh1[16 + r16];
#pragma unroll
        for (int reg = 0; reg < 4; ++reg) {
            int rr = rloc + reg;
            shm[rr * 36 + r16]      = fmaxf(d0[reg] + hb0, 0.f);
            shm[rr * 36 + 16 + r16] = fmaxf(d1[reg] + hb1, 0.f);
        }
    }
    __syncthreads();

    // stage 3: out = hmid @ Wh2 + bh2
    {
        int m = tid >> 2, a = tid & 3;
        if (a < NACT) {
            float o = bh2[a];
            const float* hp = &shm[m * 36];
            const float* wp = &sW2[a * DH];
#pragma unroll
            for (int k = 0; k < DH; k += 4) {
                f32x4 hv = *reinterpret_cast<const f32x4*>(&hp[k]);
                f32x4 wv = *reinterpret_cast<const f32x4*>(&wp[k]);
                o += hv.x * wv.x + hv.y * wv.y + hv.z * wv.z + hv.w * wv.w;
            }
            out[(base + m) * NACT + a] = o;
        }
    }
}

extern "C" void kernel_launch(void* const* d_in, const int* in_sizes, int n_in,
                              void* d_out, int out_size, void* d_ws, size_t ws_size,
                              hipStream_t stream) {
    const float* x   = (const float*)d_in[0];
    const int*   ei  = (const int*)d_in[1];
    const int*   src = ei;
    const int*   dst = ei + NE;
    const float* Wl1 = (const float*)d_in[2];
    const float* bl1 = (const float*)d_in[3];
    const float* Wr1 = (const float*)d_in[4];
    const float* Wl2 = (const float*)d_in[5];
    const float* bl2 = (const float*)d_in[6];
    const float* Wr2 = (const float*)d_in[7];
    const float* Wl3 = (const float*)d_in[8];
    const float* bl3 = (const float*)d_in[9];
    const float* Wr3 = (const float*)d_in[10];
    const float* Wh1 = (const float*)d_in[11];
    const float* bh1 = (const float*)d_in[12];
    const float* Wh2 = (const float*)d_in[13];
    const float* bh2 = (const float*)d_in[14];
    float* out = (float*)d_out;

    int* degI      = (int*)d_ws;               // NN
    int* bucket    = degI + NN;                // NBKT (zeroed together with degI)
    int* startP    = bucket + NBKT;            // NN
    int* bsum      = startP + NN;              // 512
    int* incl      = bsum + 512;               // PADN
    int* adj       = incl + PADN;              // NE
    unsigned* ebuf = (unsigned*)(adj + NE);    // NBKT*CAPB
    u16* B1t       = (u16*)(ebuf + NBKT * CAPB); // 1024
    u16* B2t       = B1t + 1024;               // 2048
    u16* B3t       = B2t + 2048;               // 2048
    u16* Bh1t      = B3t + 2048;               // 1024
    bf*  hA        = (bf*)(Bh1t + 1024);       // DH*NN
    bf*  hB        = hA + DH * NN;             // DH*NN

    hipMemsetAsync(degI, 0, (NN + NBKT) * sizeof(int), stream);

    prep_weights<<<1, 256, 0, stream>>>(Wl1, Wr1, Wl2, Wr2, Wl3, Wr3, Wh1,
                                        B1t, B2t, B3t, Bh1t);

    // ---- build CSR: 782-way partition -> per-bucket LDS count/fill (no global atomics) ----
    partition_edges<<<PA, 256, 0, stream>>>(src, dst, bucket, ebuf);
    count_local<<<NBKT, 256, 0, stream>>>(bucket, ebuf, degI);
    scanA<<<NBLK, 256, 0, stream>>>(degI, incl, bsum);
    scanB<<<1, 512, 0, stream>>>(bsum);
    scanC<<<NBLK, 256, 0, stream>>>(incl, degI, bsum, startP);
    fill_local<<<NBKT, 256, 0, stream>>>(bucket, ebuf, startP, adj);

    // ---- layers ----
    layer1_mfma<<<LG32, 128, 0, stream>>>(x, degI, startP, adj, B1t, bl1, hA);
    layer2_mfma<<<LG32, 128, 0, stream>>>(hA, degI, startP, adj, B2t, bl2, hB);
    layer3_mfma<<<LG32, 128, 0, stream>>>(hB, degI, startP, adj, B3t, bl3,
                                          Bh1t, bh1, Wh2, bh2, out);
}

// Round 14
// 222.521 us; speedup vs baseline: 1.5079x; 1.0247x over previous
//
#include <hip/hip_runtime.h>
#include <hip/hip_bf16.h>

#define NN 100000
#define NE 1600000
#define DIN 8
#define DH 32
#define NACT 3
#define BKN 128           // nodes per bucket
#define NBKT 782          // ceil(NN/BKN)
#define CAPB 3072         // per-bucket capacity (mean 2048, +22 sigma)
#define PA 128            // partition blocks
#define ECA (NE / PA)     // 12500 edges per chunk, mult of 4
#define LG32 (NN / 32)    // 3125 blocks x 32 nodes (exact)

typedef __hip_bfloat16 bf;
typedef unsigned short u16;
typedef __attribute__((ext_vector_type(8))) short bf16x8;
typedef __attribute__((ext_vector_type(4))) float f32x4;

__device__ __forceinline__ float bflo(unsigned u) { return __uint_as_float(u << 16); }
__device__ __forceinline__ float bfhi(unsigned u) { return __uint_as_float(u & 0xffff0000u); }
__device__ __forceinline__ unsigned pk2(float lo, float hi) {
    union { bf b; unsigned short u; } cl, ch;
    cl.b = __float2bfloat16(lo); ch.b = __float2bfloat16(hi);
    return (unsigned)cl.u | ((unsigned)ch.u << 16);
}

// ---------------- weight prep (bf16 transposed panels) ----------------
__launch_bounds__(256)
__global__ void prep_weights(const float* __restrict__ Wl1, const float* __restrict__ Wr1,
                             const float* __restrict__ Wl2, const float* __restrict__ Wr2,
                             const float* __restrict__ Wl3, const float* __restrict__ Wr3,
                             const float* __restrict__ Wh1,
                             u16* __restrict__ B1t, u16* __restrict__ B2t,
                             u16* __restrict__ B3t, u16* __restrict__ Bh1t) {
    int tid = threadIdx.x;
    for (int idx = tid; idx < 1024; idx += 256) {
        int j = idx >> 5, k = idx & 31;
        float v = (k < 8) ? Wl1[k * DH + j] : ((k < 16) ? Wr1[(k - 8) * DH + j] : 0.0f);
        reinterpret_cast<bf*>(B1t)[j * 32 + k] = __float2bfloat16(v);
    }
    for (int idx = tid; idx < 2048; idx += 256) {
        int j = idx >> 6, k = idx & 63;
        float v = (k < 32) ? Wl2[k * DH + j] : Wr2[(k - 32) * DH + j];
        reinterpret_cast<bf*>(B2t)[j * 64 + k] = __float2bfloat16(v);
    }
    for (int idx = tid; idx < 2048; idx += 256) {
        int j = idx >> 6, k = idx & 63;
        float v = (k < 32) ? Wl3[k * DH + j] : Wr3[(k - 32) * DH + j];
        reinterpret_cast<bf*>(B3t)[j * 64 + k] = __float2bfloat16(v);
    }
    for (int idx = tid; idx < 1024; idx += 256) {
        int j = idx >> 5, k = idx & 31;
        reinterpret_cast<bf*>(Bh1t)[j * 32 + k] = __float2bfloat16(Wh1[k * DH + j]);
    }
}

// ---------------- phase A: 782-way radix partition by dst/128 ----------------
// packed entry: (src << 7) | (dst & 127);  src < 2^17
__launch_bounds__(256)
__global__ void partition_edges(const int* __restrict__ src, const int* __restrict__ dst,
                                int* __restrict__ bucket_cnt, unsigned* __restrict__ ebuf) {
    __shared__ int lcnt[NBKT];
    __shared__ int lbase[NBKT];
    int tid = threadIdx.x;
    for (int r = tid; r < NBKT; r += 256) lcnt[r] = 0;
    __syncthreads();

    int e0 = blockIdx.x * ECA;
    // pass 1: count
    for (int e = e0 + tid * 4; e < e0 + ECA; e += 1024) {
        int4 d4 = *reinterpret_cast<const int4*>(&dst[e]);
        atomicAdd(&lcnt[(unsigned)d4.x >> 7], 1);
        atomicAdd(&lcnt[(unsigned)d4.y >> 7], 1);
        atomicAdd(&lcnt[(unsigned)d4.z >> 7], 1);
        atomicAdd(&lcnt[(unsigned)d4.w >> 7], 1);
    }
    __syncthreads();
    // reserve contiguous runs per bucket (only global atomics in the build)
    for (int r = tid; r < NBKT; r += 256) {
        lbase[r] = atomicAdd(&bucket_cnt[r], lcnt[r]);
        lcnt[r] = 0;
    }
    __syncthreads();
    // pass 2: scatter (chunk re-read is L2-hot); runs are contiguous per block
    for (int e = e0 + tid * 4; e < e0 + ECA; e += 1024) {
        int4 d4 = *reinterpret_cast<const int4*>(&dst[e]);
        int4 s4 = *reinterpret_cast<const int4*>(&src[e]);
        int r, p;
        r = (unsigned)d4.x >> 7; p = lbase[r] + atomicAdd(&lcnt[r], 1);
        if (p < CAPB) ebuf[r * CAPB + p] = ((unsigned)s4.x << 7) | ((unsigned)d4.x & 127u);
        r = (unsigned)d4.y >> 7; p = lbase[r] + atomicAdd(&lcnt[r], 1);
        if (p < CAPB) ebuf[r * CAPB + p] = ((unsigned)s4.y << 7) | ((unsigned)d4.y & 127u);
        r = (unsigned)d4.z >> 7; p = lbase[r] + atomicAdd(&lcnt[r], 1);
        if (p < CAPB) ebuf[r * CAPB + p] = ((unsigned)s4.z << 7) | ((unsigned)d4.z & 127u);
        r = (unsigned)d4.w >> 7; p = lbase[r] + atomicAdd(&lcnt[r], 1);
        if (p < CAPB) ebuf[r * CAPB + p] = ((unsigned)s4.w << 7) | ((unsigned)d4.w & 127u);
    }
}

// ---------------- scan bucket counts -> bucket_base (1 block) ----------------
__launch_bounds__(256)
__global__ void scan_buckets(const int* __restrict__ bucket_cnt, int* __restrict__ bucket_base) {
    __shared__ int s[256];
    int tid = threadIdx.x;
    int i0 = tid * 4;
    int v0 = (i0 + 0 < NBKT) ? min(bucket_cnt[i0 + 0], CAPB) : 0;
    int v1 = (i0 + 1 < NBKT) ? min(bucket_cnt[i0 + 1], CAPB) : 0;
    int v2 = (i0 + 2 < NBKT) ? min(bucket_cnt[i0 + 2], CAPB) : 0;
    int v3 = (i0 + 3 < NBKT) ? min(bucket_cnt[i0 + 3], CAPB) : 0;
    s[tid] = v0 + v1 + v2 + v3;
    __syncthreads();
#pragma unroll
    for (int off = 1; off < 256; off <<= 1) {
        int t = (tid >= off) ? s[tid - off] : 0;
        __syncthreads();
        s[tid] += t;
        __syncthreads();
    }
    int prev = (tid > 0) ? s[tid - 1] : 0;
    if (i0 + 0 < NBKT) bucket_base[i0 + 0] = prev;
    if (i0 + 1 < NBKT) bucket_base[i0 + 1] = prev + v0;
    if (i0 + 2 < NBKT) bucket_base[i0 + 2] = prev + v0 + v1;
    if (i0 + 3 < NBKT) bucket_base[i0 + 3] = prev + v0 + v1 + v2;
}

// ---------------- fused per-bucket: hist + local scan + degI/startP + fill ----------------
__launch_bounds__(256)
__global__ void fill_fused(const int* __restrict__ bucket_cnt, const int* __restrict__ bucket_base,
                           const unsigned* __restrict__ ebuf,
                           int* __restrict__ degI, int* __restrict__ startP,
                           int* __restrict__ adj) {
    __shared__ unsigned sc[CAPB];
    __shared__ int cnt[BKN];
    __shared__ int lofs[BKN];
    __shared__ int cur[BKN];
    int tid = threadIdx.x;
    int r = blockIdx.x;
    int n = min(bucket_cnt[r], CAPB);
    if (tid < BKN) { cnt[tid] = 0; cur[tid] = 0; }
    __syncthreads();
    const unsigned* eb = ebuf + r * CAPB;
    for (int i = tid; i < n; i += 256) {
        unsigned v = eb[i];
        sc[i] = v;
        atomicAdd(&cnt[v & 127u], 1);
    }
    __syncthreads();
    // 128-bin inclusive scan (Hillis-Steele), then convert to exclusive
    if (tid < BKN) lofs[tid] = cnt[tid];
    __syncthreads();
#pragma unroll
    for (int off = 1; off < BKN; off <<= 1) {
        int t = 0;
        if (tid < BKN && tid >= off) t = lofs[tid - off];
        __syncthreads();
        if (tid < BKN) lofs[tid] += t;
        __syncthreads();
    }
    if (tid < BKN) lofs[tid] -= cnt[tid];  // exclusive
    __syncthreads();
    int gbase = bucket_base[r];
    int node = r * BKN + tid;
    if (tid < BKN && node < NN) {
        degI[node]   = cnt[tid];
        startP[node] = gbase + lofs[tid];
    }
    __syncthreads();
    // scatter from LDS into the bucket's private contiguous adj window
    for (int i = tid; i < n; i += 256) {
        unsigned v = sc[i];
        int d = v & 127u;
        int p = atomicAdd(&cur[d], 1);     // LDS atomic
        adj[gbase + lofs[d] + p] = (int)(v >> 7);
    }
}

// ============ layer 1: uniform-shfl gather(d=8,f32) -> A[32][72] -> MFMA ============
__launch_bounds__(128)
__global__ void layer1_mfma(const float* __restrict__ x, const int* __restrict__ degI,
                            const int* __restrict__ start, const int* __restrict__ adj,
                            const u16* __restrict__ Bt, const float* __restrict__ blv,
                            bf* __restrict__ hout) {
    __shared__ __align__(16) short sA[32 * 72];
    int tid = threadIdx.x;
    int base = blockIdx.x * 32;

    {   // zero pad k=16..31 region
        int row = tid >> 2, part = tid & 3;
        *reinterpret_cast<uint2*>(&sA[row * 72 + 16 + part * 4]) = make_uint2(0u, 0u);
    }

    int g = tid >> 5, t = tid & 31;
    int nb = t >> 1, q = t & 1;
    int nbase = base + g * 8;
    int dgv = 0, stv = 0;
    if (t < 8) { dgv = degI[nbase + t]; stv = start[nbase + t]; }

#pragma unroll 4
    for (int i = 0; i < 8; ++i) {
        int dg  = __shfl(dgv, i, 32);
        int row = __shfl(stv, i, 32);
        int node = nbase + i;
        int idxreg = (t < dg) ? adj[row + t] : 0;
        float4 xv;
        if (t == 2 || t == 3)
            xv = *reinterpret_cast<const float4*>(&x[node * DIN + (t - 2) * 4]);
        float a[4] = {0.f, 0.f, 0.f, 0.f};
        int lim = min(dg, 32);
        int nit = (lim + 15) >> 4;
        for (int j = 0; j < nit; ++j) {
            int k = nb + j * 16;
            int s = __shfl(idxreg, k, 32);
            float4 v = *reinterpret_cast<const float4*>(&x[s * DIN + q * 4]);
            if (k < lim) { a[0] += v.x; a[1] += v.y; a[2] += v.z; a[3] += v.w; }
        }
        for (int k = 32 + nb; k < dg; k += 16) {
            int s = adj[row + k];
            float4 v = *reinterpret_cast<const float4*>(&x[s * DIN + q * 4]);
            a[0] += v.x; a[1] += v.y; a[2] += v.z; a[3] += v.w;
        }
#pragma unroll
        for (int m = 0; m < 4; ++m) {
            a[m] += __shfl_xor(a[m], 2);
            a[m] += __shfl_xor(a[m], 4);
            a[m] += __shfl_xor(a[m], 8);
            a[m] += __shfl_xor(a[m], 16);
        }
        int nrow = g * 8 + i;
        if (t < 2) {
            float inv = 1.0f / fmaxf((float)dg, 1.0f);
            uint2 mm;
            mm.x = pk2(a[0] * inv, a[1] * inv);
            mm.y = pk2(a[2] * inv, a[3] * inv);
            *reinterpret_cast<uint2*>(&sA[nrow * 72 + t * 4]) = mm;
        } else if (t < 4) {
            uint2 xm;
            xm.x = pk2(xv.x, xv.y);
            xm.y = pk2(xv.z, xv.w);
            *reinterpret_cast<uint2*>(&sA[nrow * 72 + 8 + (t - 2) * 4]) = xm;
        }
    }
    __syncthreads();

    int wid = tid >> 6, lane = tid & 63;
    int r16 = lane & 15, k8 = (lane >> 4) * 8;
    bf16x8 av = *reinterpret_cast<const bf16x8*>(&sA[(wid * 16 + r16) * 72 + k8]);
    bf16x8 b0 = *reinterpret_cast<const bf16x8*>(&Bt[r16 * 32 + k8]);
    bf16x8 b1 = *reinterpret_cast<const bf16x8*>(&Bt[(16 + r16) * 32 + k8]);
    f32x4 acc0 = {0.f, 0.f, 0.f, 0.f}, acc1 = {0.f, 0.f, 0.f, 0.f};
    acc0 = __builtin_amdgcn_mfma_f32_16x16x32_bf16(av, b0, acc0, 0, 0, 0);
    acc1 = __builtin_amdgcn_mfma_f32_16x16x32_bf16(av, b1, acc1, 0, 0, 0);
    float bias0 = blv[r16], bias1 = blv[16 + r16];
    int rbase = base + wid * 16 + (lane >> 4) * 4;
#pragma unroll
    for (int reg = 0; reg < 4; ++reg) {
        int node = rbase + reg;
        hout[node * DH + r16]      = __float2bfloat16(fmaxf(acc0[reg] + bias0, 0.f));
        hout[node * DH + 16 + r16] = __float2bfloat16(fmaxf(acc1[reg] + bias1, 0.f));
    }
}

// ============ shared gather for d=32 bf16 panels (uniform shfl loop) ============
__device__ __forceinline__ void gather32(const bf* __restrict__ hin,
                                         const int* __restrict__ degI,
                                         const int* __restrict__ start,
                                         const int* __restrict__ adj,
                                         short* sA, int base, int tid) {
    int g = tid >> 5, t = tid & 31;
    int nb = t >> 2, q = t & 3;
    int nbase = base + g * 8;
    int dgv = 0, stv = 0;
    if (t < 8) { dgv = degI[nbase + t]; stv = start[nbase + t]; }

#pragma unroll 4
    for (int i = 0; i < 8; ++i) {
        int dg  = __shfl(dgv, i, 32);
        int row = __shfl(stv, i, 32);
        int node = nbase + i;
        int idxreg = (t < dg) ? adj[row + t] : 0;
        uint4 xru;
        if ((t & 28) == 4)
            xru = *reinterpret_cast<const uint4*>(&hin[node * DH + (t - 4) * 8]);
        float a[8] = {0.f, 0.f, 0.f, 0.f, 0.f, 0.f, 0.f, 0.f};
        int lim = min(dg, 32);
        int nit = (lim + 7) >> 3;
        for (int j = 0; j < nit; ++j) {
            int k = nb + j * 8;
            int s = __shfl(idxreg, k, 32);
            uint4 u = *reinterpret_cast<const uint4*>(&hin[s * DH + q * 8]);
            if (k < lim) {
                a[0] += bflo(u.x); a[1] += bfhi(u.x);
                a[2] += bflo(u.y); a[3] += bfhi(u.y);
                a[4] += bflo(u.z); a[5] += bfhi(u.z);
                a[6] += bflo(u.w); a[7] += bfhi(u.w);
            }
        }
        for (int k = 32 + nb; k < dg; k += 8) {
            int s = adj[row + k];
            uint4 u = *reinterpret_cast<const uint4*>(&hin[s * DH + q * 8]);
            a[0] += bflo(u.x); a[1] += bfhi(u.x);
            a[2] += bflo(u.y); a[3] += bfhi(u.y);
            a[4] += bflo(u.z); a[5] += bfhi(u.z);
            a[6] += bflo(u.w); a[7] += bfhi(u.w);
        }
#pragma unroll
        for (int m = 0; m < 8; ++m) {
            a[m] += __shfl_xor(a[m], 4);
            a[m] += __shfl_xor(a[m], 8);
            a[m] += __shfl_xor(a[m], 16);
        }
        int nrow = g * 8 + i;
        if (t < 4) {
            float inv = 1.0f / fmaxf((float)dg, 1.0f);
            uint4 mm;
            mm.x = pk2(a[0] * inv, a[1] * inv);
            mm.y = pk2(a[2] * inv, a[3] * inv);
            mm.z = pk2(a[4] * inv, a[5] * inv);
            mm.w = pk2(a[6] * inv, a[7] * inv);
            *reinterpret_cast<uint4*>(&sA[nrow * 72 + t * 8]) = mm;
        } else if (t < 8) {
            *reinterpret_cast<uint4*>(&sA[nrow * 72 + 32 + (t - 4) * 8]) = xru;
        }
    }
}

// ============ layer 2 ============
__launch_bounds__(128)
__global__ void layer2_mfma(const bf* __restrict__ hin, const int* __restrict__ degI,
                            const int* __restrict__ start, const int* __restrict__ adj,
                            const u16* __restrict__ Bt, const float* __restrict__ blv,
                            bf* __restrict__ hout) {
    __shared__ __align__(16) short sA[32 * 72];
    int tid = threadIdx.x;
    int base = blockIdx.x * 32;

    gather32(hin, degI, start, adj, sA, base, tid);
    __syncthreads();

    int wid = tid >> 6, lane = tid & 63;
    int r16 = lane & 15, k8 = (lane >> 4) * 8;
    const short* ap = &sA[(wid * 16 + r16) * 72];
    bf16x8 av0 = *reinterpret_cast<const bf16x8*>(&ap[k8]);
    bf16x8 av1 = *reinterpret_cast<const bf16x8*>(&ap[32 + k8]);
    const u16* b0p = &Bt[r16 * 64];
    const u16* b1p = &Bt[(16 + r16) * 64];
    bf16x8 b00 = *reinterpret_cast<const bf16x8*>(&b0p[k8]);
    bf16x8 b01 = *reinterpret_cast<const bf16x8*>(&b0p[32 + k8]);
    bf16x8 b10 = *reinterpret_cast<const bf16x8*>(&b1p[k8]);
    bf16x8 b11 = *reinterpret_cast<const bf16x8*>(&b1p[32 + k8]);
    f32x4 acc0 = {0.f, 0.f, 0.f, 0.f}, acc1 = {0.f, 0.f, 0.f, 0.f};
    acc0 = __builtin_amdgcn_mfma_f32_16x16x32_bf16(av0, b00, acc0, 0, 0, 0);
    acc0 = __builtin_amdgcn_mfma_f32_16x16x32_bf16(av1, b01, acc0, 0, 0, 0);
    acc1 = __builtin_amdgcn_mfma_f32_16x16x32_bf16(av0, b10, acc1, 0, 0, 0);
    acc1 = __builtin_amdgcn_mfma_f32_16x16x32_bf16(av1, b11, acc1, 0, 0, 0);
    float bias0 = blv[r16], bias1 = blv[16 + r16];
    int rbase = base + wid * 16 + (lane >> 4) * 4;
#pragma unroll
    for (int reg = 0; reg < 4; ++reg) {
        int node = rbase + reg;
        hout[node * DH + r16]      = __float2bfloat16(fmaxf(acc0[reg] + bias0, 0.f));
        hout[node * DH + 16 + r16] = __float2bfloat16(fmaxf(acc1[reg] + bias1, 0.f));
    }
}

// ============ layer 3 + head (LDS overlaid: sA -> h3 -> hmid) ============
__launch_bounds__(128)
__global__ void layer3_mfma(const bf* __restrict__ hin, const int* __restrict__ degI,
                            const int* __restrict__ start, const int* __restrict__ adj,
                            const u16* __restrict__ B3t, const float* __restrict__ bl3,
                            const u16* __restrict__ Bh1t, const float* __restrict__ bh1,
                            const float* __restrict__ Wh2, const float* __restrict__ bh2,
                            float* __restrict__ out) {
    __shared__ __align__(16) short sA[32 * 72];
    __shared__ float sW2[NACT * DH];
    int tid = threadIdx.x;
    int base = blockIdx.x * 32;

    if (tid < NACT * DH) {
        int a = tid >> 5, k = tid & 31;
        sW2[a * DH + k] = Wh2[k * NACT + a];
    }

    gather32(hin, degI, start, adj, sA, base, tid);
    __syncthreads();

    int wid = tid >> 6, lane = tid & 63;
    int r16 = lane & 15, k8 = (lane >> 4) * 8;
    int rloc = wid * 16 + (lane >> 4) * 4;

    // stage 1: SAGE conv
    f32x4 acc0 = {0.f, 0.f, 0.f, 0.f}, acc1 = {0.f, 0.f, 0.f, 0.f};
    {
        const short* ap = &sA[(wid * 16 + r16) * 72];
        bf16x8 av0 = *reinterpret_cast<const bf16x8*>(&ap[k8]);
        bf16x8 av1 = *reinterpret_cast<const bf16x8*>(&ap[32 + k8]);
        const u16* b0p = &B3t[r16 * 64];
        const u16* b1p = &B3t[(16 + r16) * 64];
        bf16x8 b00 = *reinterpret_cast<const bf16x8*>(&b0p[k8]);
        bf16x8 b01 = *reinterpret_cast<const bf16x8*>(&b0p[32 + k8]);
        bf16x8 b10 = *reinterpret_cast<const bf16x8*>(&b1p[k8]);
        bf16x8 b11 = *reinterpret_cast<const bf16x8*>(&b1p[32 + k8]);
        acc0 = __builtin_amdgcn_mfma_f32_16x16x32_bf16(av0, b00, acc0, 0, 0, 0);
        acc0 = __builtin_amdgcn_mfma_f32_16x16x32_bf16(av1, b01, acc0, 0, 0, 0);
        acc1 = __builtin_amdgcn_mfma_f32_16x16x32_bf16(av0, b10, acc1, 0, 0, 0);
        acc1 = __builtin_amdgcn_mfma_f32_16x16x32_bf16(av1, b11, acc1, 0, 0, 0);
    }
    __syncthreads();

    bf* h3b = reinterpret_cast<bf*>(sA);   // overlay: [32][40] bf16
    {
        float bias0 = bl3[r16], bias1 = bl3[16 + r16];
#pragma unroll
        for (int reg = 0; reg < 4; ++reg) {
            int rr = rloc + reg;
            h3b[rr * 40 + r16]      = __float2bfloat16(fmaxf(acc0[reg] + bias0, 0.f));
            h3b[rr * 40 + 16 + r16] = __float2bfloat16(fmaxf(acc1[reg] + bias1, 0.f));
        }
    }
    __syncthreads();

    // stage 2: hmid = relu(h3 @ Wh1 + bh1)
    f32x4 d0 = {0.f, 0.f, 0.f, 0.f}, d1 = {0.f, 0.f, 0.f, 0.f};
    {
        bf16x8 av = *reinterpret_cast<const bf16x8*>(&h3b[(wid * 16 + r16) * 40 + k8]);
        bf16x8 b0 = *reinterpret_cast<const bf16x8*>(&Bh1t[r16 * 32 + k8]);
        bf16x8 b1 = *reinterpret_cast<const bf16x8*>(&Bh1t[(16 + r16) * 32 + k8]);
        d0 = __builtin_amdgcn_mfma_f32_16x16x32_bf16(av, b0, d0, 0, 0, 0);
        d1 = __builtin_amdgcn_mfma_f32_16x16x32_bf16(av, b1, d1, 0, 0, 0);
    }
    __syncthreads();

    float* shm = reinterpret_cast<float*>(sA);   // overlay: [32][36] f32
    {
        float hb0 = bh1[r16], hb1 = bh1[16 + r16];
#pragma unroll
        for (int reg = 0; reg < 4; ++reg) {
            int rr = rloc + reg;
            shm[rr * 36 + r16]      = fmaxf(d0[reg] + hb0, 0.f);
            shm[rr * 36 + 16 + r16] = fmaxf(d1[reg] + hb1, 0.f);
        }
    }
    __syncthreads();

    // stage 3: out = hmid @ Wh2 + bh2
    {
        int m = tid >> 2, a = tid & 3;
        if (a < NACT) {
            float o = bh2[a];
            const float* hp = &shm[m * 36];
            const float* wp = &sW2[a * DH];
#pragma unroll
            for (int k = 0; k < DH; k += 4) {
                f32x4 hv = *reinterpret_cast<const f32x4*>(&hp[k]);
                f32x4 wv = *reinterpret_cast<const f32x4*>(&wp[k]);
                o += hv.x * wv.x + hv.y * wv.y + hv.z * wv.z + hv.w * wv.w;
            }
            out[(base + m) * NACT + a] = o;
        }
    }
}

extern "C" void kernel_launch(void* const* d_in, const int* in_sizes, int n_in,
                              void* d_out, int out_size, void* d_ws, size_t ws_size,
                              hipStream_t stream) {
    const float* x   = (const float*)d_in[0];
    const int*   ei  = (const int*)d_in[1];
    const int*   src = ei;
    const int*   dst = ei + NE;
    const float* Wl1 = (const float*)d_in[2];
    const float* bl1 = (const float*)d_in[3];
    const float* Wr1 = (const float*)d_in[4];
    const float* Wl2 = (const float*)d_in[5];
    const float* bl2 = (const float*)d_in[6];
    const float* Wr2 = (const float*)d_in[7];
    const float* Wl3 = (const float*)d_in[8];
    const float* bl3 = (const float*)d_in[9];
    const float* Wr3 = (const float*)d_in[10];
    const float* Wh1 = (const float*)d_in[11];
    const float* bh1 = (const float*)d_in[12];
    const float* Wh2 = (const float*)d_in[13];
    const float* bh2 = (const float*)d_in[14];
    float* out = (float*)d_out;

    int* bucket      = (int*)d_ws;               // NBKT
    int* bucket_base = bucket + NBKT;            // NBKT
    int* degI        = bucket_base + NBKT;       // NN
    int* startP      = degI + NN;                // NN
    int* adj         = startP + NN;              // NE
    unsigned* ebuf   = (unsigned*)(adj + NE);    // NBKT*CAPB
    u16* B1t         = (u16*)(ebuf + NBKT * CAPB); // 1024
    u16* B2t         = B1t + 1024;               // 2048
    u16* B3t         = B2t + 2048;               // 2048
    u16* Bh1t        = B3t + 2048;               // 1024
    bf*  hA          = (bf*)(Bh1t + 1024);       // DH*NN
    bf*  hB          = hA + DH * NN;             // DH*NN

    hipMemsetAsync(bucket, 0, NBKT * sizeof(int), stream);

    prep_weights<<<1, 256, 0, stream>>>(Wl1, Wr1, Wl2, Wr2, Wl3, Wr3, Wh1,
                                        B1t, B2t, B3t, Bh1t);

    // ---- build CSR: partition -> bucket scan -> fused per-bucket count+scan+fill ----
    partition_edges<<<PA, 256, 0, stream>>>(src, dst, bucket, ebuf);
    scan_buckets<<<1, 256, 0, stream>>>(bucket, bucket_base);
    fill_fused<<<NBKT, 256, 0, stream>>>(bucket, bucket_base, ebuf, degI, startP, adj);

    // ---- layers ----
    layer1_mfma<<<LG32, 128, 0, stream>>>(x, degI, startP, adj, B1t, bl1, hA);
    layer2_mfma<<<LG32, 128, 0, stream>>>(hA, degI, startP, adj, B2t, bl2, hB);
    layer3_mfma<<<LG32, 128, 0, stream>>>(hB, degI, startP, adj, B3t, bl3,
                                          Bh1t, bh1, Wh2, bh2, out);
}

// Round 15
// 216.640 us; speedup vs baseline: 1.5488x; 1.0271x over previous
//
#include <hip/hip_runtime.h>
#include <hip/hip_bf16.h>

#define NN 100000
#define NE 1600000
#define DIN 8
#define DH 32
#define NACT 3
#define BKN 128           // nodes per bucket
#define NBKT 782          // ceil(NN/BKN)
#define CAPB 3072         // per-bucket capacity (mean 2048, +22 sigma)
#define PA 128            // partition blocks
#define ECA (NE / PA)     // 12500 edges per chunk, mult of 4
#define LG32 (NN / 32)    // 3125 blocks x 32 nodes (exact)

typedef __hip_bfloat16 bf;
typedef unsigned short u16;
typedef __attribute__((ext_vector_type(8))) short bf16x8;
typedef __attribute__((ext_vector_type(4))) float f32x4;

__device__ __forceinline__ float bflo(unsigned u) { return __uint_as_float(u << 16); }
__device__ __forceinline__ float bfhi(unsigned u) { return __uint_as_float(u & 0xffff0000u); }
__device__ __forceinline__ unsigned pk2(float lo, float hi) {
    union { bf b; unsigned short u; } cl, ch;
    cl.b = __float2bfloat16(lo); ch.b = __float2bfloat16(hi);
    return (unsigned)cl.u | ((unsigned)ch.u << 16);
}

// ---------------- weight prep (bf16 transposed panels) ----------------
__launch_bounds__(256)
__global__ void prep_weights(const float* __restrict__ Wl1, const float* __restrict__ Wr1,
                             const float* __restrict__ Wl2, const float* __restrict__ Wr2,
                             const float* __restrict__ Wl3, const float* __restrict__ Wr3,
                             const float* __restrict__ Wh1,
                             u16* __restrict__ B1t, u16* __restrict__ B2t,
                             u16* __restrict__ B3t, u16* __restrict__ Bh1t) {
    int tid = threadIdx.x;
    for (int idx = tid; idx < 1024; idx += 256) {
        int j = idx >> 5, k = idx & 31;
        float v = (k < 8) ? Wl1[k * DH + j] : ((k < 16) ? Wr1[(k - 8) * DH + j] : 0.0f);
        reinterpret_cast<bf*>(B1t)[j * 32 + k] = __float2bfloat16(v);
    }
    for (int idx = tid; idx < 2048; idx += 256) {
        int j = idx >> 6, k = idx & 63;
        float v = (k < 32) ? Wl2[k * DH + j] : Wr2[(k - 32) * DH + j];
        reinterpret_cast<bf*>(B2t)[j * 64 + k] = __float2bfloat16(v);
    }
    for (int idx = tid; idx < 2048; idx += 256) {
        int j = idx >> 6, k = idx & 63;
        float v = (k < 32) ? Wl3[k * DH + j] : Wr3[(k - 32) * DH + j];
        reinterpret_cast<bf*>(B3t)[j * 64 + k] = __float2bfloat16(v);
    }
    for (int idx = tid; idx < 1024; idx += 256) {
        int j = idx >> 5, k = idx & 31;
        reinterpret_cast<bf*>(Bh1t)[j * 32 + k] = __float2bfloat16(Wh1[k * DH + j]);
    }
}

// ---------------- phase A: 782-way radix partition by dst/128 ----------------
// packed entry: (src << 7) | (dst & 127);  src < 2^17
__launch_bounds__(256)
__global__ void partition_edges(const int* __restrict__ src, const int* __restrict__ dst,
                                int* __restrict__ bucket_cnt, unsigned* __restrict__ ebuf) {
    __shared__ int lcnt[NBKT];
    __shared__ int lbase[NBKT];
    int tid = threadIdx.x;
    for (int r = tid; r < NBKT; r += 256) lcnt[r] = 0;
    __syncthreads();

    int e0 = blockIdx.x * ECA;
    // pass 1: count
    for (int e = e0 + tid * 4; e < e0 + ECA; e += 1024) {
        int4 d4 = *reinterpret_cast<const int4*>(&dst[e]);
        atomicAdd(&lcnt[(unsigned)d4.x >> 7], 1);
        atomicAdd(&lcnt[(unsigned)d4.y >> 7], 1);
        atomicAdd(&lcnt[(unsigned)d4.z >> 7], 1);
        atomicAdd(&lcnt[(unsigned)d4.w >> 7], 1);
    }
    __syncthreads();
    // reserve contiguous runs per bucket (only global atomics in the build)
    for (int r = tid; r < NBKT; r += 256) {
        lbase[r] = atomicAdd(&bucket_cnt[r], lcnt[r]);
        lcnt[r] = 0;
    }
    __syncthreads();
    // pass 2: scatter (chunk re-read is L2-hot); runs are contiguous per block
    for (int e = e0 + tid * 4; e < e0 + ECA; e += 1024) {
        int4 d4 = *reinterpret_cast<const int4*>(&dst[e]);
        int4 s4 = *reinterpret_cast<const int4*>(&src[e]);
        int r, p;
        r = (unsigned)d4.x >> 7; p = lbase[r] + atomicAdd(&lcnt[r], 1);
        if (p < CAPB) ebuf[r * CAPB + p] = ((unsigned)s4.x << 7) | ((unsigned)d4.x & 127u);
        r = (unsigned)d4.y >> 7; p = lbase[r] + atomicAdd(&lcnt[r], 1);
        if (p < CAPB) ebuf[r * CAPB + p] = ((unsigned)s4.y << 7) | ((unsigned)d4.y & 127u);
        r = (unsigned)d4.z >> 7; p = lbase[r] + atomicAdd(&lcnt[r], 1);
        if (p < CAPB) ebuf[r * CAPB + p] = ((unsigned)s4.z << 7) | ((unsigned)d4.z & 127u);
        r = (unsigned)d4.w >> 7; p = lbase[r] + atomicAdd(&lcnt[r], 1);
        if (p < CAPB) ebuf[r * CAPB + p] = ((unsigned)s4.w << 7) | ((unsigned)d4.w & 127u);
    }
}

// ---------------- fused per-bucket: base + hist + local scan + degI/startP + fill ----------------
__launch_bounds__(256)
__global__ void fill_fused(const int* __restrict__ bucket_cnt,
                           const unsigned* __restrict__ ebuf,
                           int* __restrict__ degI, int* __restrict__ startP,
                           int* __restrict__ adj) {
    __shared__ unsigned sc[CAPB];
    __shared__ int cnt[BKN];
    __shared__ int lofs[BKN];
    __shared__ int cur[BKN];
    __shared__ int sred[256];
    int tid = threadIdx.x;
    int r = blockIdx.x;
    // gbase = sum_{b<r} min(cnt[b],CAPB)  (replaces separate scan kernel)
    int part = 0;
    for (int b = tid; b < r; b += 256) part += min(bucket_cnt[b], CAPB);
    sred[tid] = part;
    if (tid < BKN) { cnt[tid] = 0; cur[tid] = 0; }
    __syncthreads();
#pragma unroll
    for (int off = 128; off > 0; off >>= 1) {
        if (tid < off) sred[tid] += sred[tid + off];
        __syncthreads();
    }
    int gbase = sred[0];

    int n = min(bucket_cnt[r], CAPB);
    const unsigned* eb = ebuf + r * CAPB;
    for (int i = tid; i < n; i += 256) {
        unsigned v = eb[i];
        sc[i] = v;
        atomicAdd(&cnt[v & 127u], 1);
    }
    __syncthreads();
    // 128-bin inclusive scan (Hillis-Steele), then convert to exclusive
    if (tid < BKN) lofs[tid] = cnt[tid];
    __syncthreads();
#pragma unroll
    for (int off = 1; off < BKN; off <<= 1) {
        int t = 0;
        if (tid < BKN && tid >= off) t = lofs[tid - off];
        __syncthreads();
        if (tid < BKN) lofs[tid] += t;
        __syncthreads();
    }
    if (tid < BKN) lofs[tid] -= cnt[tid];  // exclusive
    __syncthreads();
    int node = r * BKN + tid;
    if (tid < BKN && node < NN) {
        degI[node]   = cnt[tid];
        startP[node] = gbase + lofs[tid];
    }
    __syncthreads();
    // scatter from LDS into the bucket's private contiguous adj window
    for (int i = tid; i < n; i += 256) {
        unsigned v = sc[i];
        int d = v & 127u;
        int p = atomicAdd(&cur[d], 1);     // LDS atomic
        adj[gbase + lofs[d] + p] = (int)(v >> 7);
    }
}

// ============ layer 1: hoisted-MLP gather(d=8,f32) -> A[32][72] -> MFMA ============
// 128 threads = 4 groups x 32 lanes; 8 nodes/group.
__launch_bounds__(128)
__global__ void layer1_mfma(const float* __restrict__ x, const int* __restrict__ degI,
                            const int* __restrict__ start, const int* __restrict__ adj,
                            const u16* __restrict__ Bt, const float* __restrict__ blv,
                            bf* __restrict__ hout) {
    __shared__ __align__(16) short sA[32 * 72];
    int tid = threadIdx.x;
    int base = blockIdx.x * 32;

    {   // zero pad k=16..31 region
        int row = tid >> 2, part = tid & 3;
        *reinterpret_cast<uint2*>(&sA[row * 72 + 16 + part * 4]) = make_uint2(0u, 0u);
    }

    int g = tid >> 5, t = tid & 31;
    int nb = t >> 1, q = t & 1;    // 16 neighbor slots x 2 half-rows(16B)
    int nbase = base + g * 8;
    int dgv = 0, stv = 0;
    if (t < 8) { dgv = degI[nbase + t]; stv = start[nbase + t]; }

    int dg[8], row[8], idxreg[8];
#pragma unroll
    for (int i = 0; i < 8; ++i) {
        dg[i]  = __shfl(dgv, i, 32);
        row[i] = __shfl(stv, i, 32);
    }
#pragma unroll
    for (int i = 0; i < 8; ++i)          // 8 outstanding adj loads
        idxreg[i] = (t < dg[i]) ? adj[row[i] + t] : 0;

    // own-row copy: 16 lanes, one float4 load each (node t>>1, half t&1)
    if (t < 16) {
        float4 xv = *reinterpret_cast<const float4*>(&x[(nbase + (t >> 1)) * DIN + (t & 1) * 4]);
        uint2 xm;
        xm.x = pk2(xv.x, xv.y);
        xm.y = pk2(xv.z, xv.w);
        *reinterpret_cast<uint2*>(&sA[(g * 8 + (t >> 1)) * 72 + 8 + (t & 1) * 4]) = xm;
    }

#pragma unroll
    for (int i = 0; i < 8; ++i) {
        float a[4] = {0.f, 0.f, 0.f, 0.f};
        int lim = min(dg[i], 32);
        int nit = (lim + 15) >> 4;   // uniform trip count: ALL lanes run the shfl
        for (int j = 0; j < nit; ++j) {
            int k = nb + j * 16;
            int s = __shfl(idxreg[i], k, 32);
            float4 v = *reinterpret_cast<const float4*>(&x[s * DIN + q * 4]);
            if (k < lim) { a[0] += v.x; a[1] += v.y; a[2] += v.z; a[3] += v.w; }
        }
        for (int k = 32 + nb; k < dg[i]; k += 16) {   // rare deg>32 tail
            int s = adj[row[i] + k];
            float4 v = *reinterpret_cast<const float4*>(&x[s * DIN + q * 4]);
            a[0] += v.x; a[1] += v.y; a[2] += v.z; a[3] += v.w;
        }
#pragma unroll
        for (int m = 0; m < 4; ++m) {
            a[m] += __shfl_xor(a[m], 2);
            a[m] += __shfl_xor(a[m], 4);
            a[m] += __shfl_xor(a[m], 8);
            a[m] += __shfl_xor(a[m], 16);
        }
        if (t < 2) {
            float inv = 1.0f / fmaxf((float)dg[i], 1.0f);
            uint2 mm;
            mm.x = pk2(a[0] * inv, a[1] * inv);
            mm.y = pk2(a[2] * inv, a[3] * inv);
            *reinterpret_cast<uint2*>(&sA[(g * 8 + i) * 72 + t * 4]) = mm;
        }
    }
    __syncthreads();

    int wid = tid >> 6, lane = tid & 63;
    int r16 = lane & 15, k8 = (lane >> 4) * 8;
    bf16x8 av = *reinterpret_cast<const bf16x8*>(&sA[(wid * 16 + r16) * 72 + k8]);
    bf16x8 b0 = *reinterpret_cast<const bf16x8*>(&Bt[r16 * 32 + k8]);
    bf16x8 b1 = *reinterpret_cast<const bf16x8*>(&Bt[(16 + r16) * 32 + k8]);
    f32x4 acc0 = {0.f, 0.f, 0.f, 0.f}, acc1 = {0.f, 0.f, 0.f, 0.f};
    acc0 = __builtin_amdgcn_mfma_f32_16x16x32_bf16(av, b0, acc0, 0, 0, 0);
    acc1 = __builtin_amdgcn_mfma_f32_16x16x32_bf16(av, b1, acc1, 0, 0, 0);
    float bias0 = blv[r16], bias1 = blv[16 + r16];
    int rbase = base + wid * 16 + (lane >> 4) * 4;
#pragma unroll
    for (int reg = 0; reg < 4; ++reg) {
        int node = rbase + reg;
        hout[node * DH + r16]      = __float2bfloat16(fmaxf(acc0[reg] + bias0, 0.f));
        hout[node * DH + 16 + r16] = __float2bfloat16(fmaxf(acc1[reg] + bias1, 0.f));
    }
}

// ============ shared gather for d=32 bf16 panels (hoisted MLP) ============
__device__ __forceinline__ void gather32(const bf* __restrict__ hin,
                                         const int* __restrict__ degI,
                                         const int* __restrict__ start,
                                         const int* __restrict__ adj,
                                         short* sA, int base, int tid) {
    int g = tid >> 5, t = tid & 31;
    int nb = t >> 2, q = t & 3;    // 8 neighbor slots x 4 quarters(16B)
    int nbase = base + g * 8;
    int dgv = 0, stv = 0;
    if (t < 8) { dgv = degI[nbase + t]; stv = start[nbase + t]; }

    int dg[8], row[8], idxreg[8];
#pragma unroll
    for (int i = 0; i < 8; ++i) {
        dg[i]  = __shfl(dgv, i, 32);
        row[i] = __shfl(stv, i, 32);
    }
#pragma unroll
    for (int i = 0; i < 8; ++i)          // 8 outstanding adj loads
        idxreg[i] = (t < dg[i]) ? adj[row[i] + t] : 0;

    // own-row copy: all 32 lanes, one uint4 load each (node t>>2, quarter t&3)
    {
        uint4 xru = *reinterpret_cast<const uint4*>(&hin[(nbase + (t >> 2)) * DH + (t & 3) * 8]);
        *reinterpret_cast<uint4*>(&sA[(g * 8 + (t >> 2)) * 72 + 32 + (t & 3) * 8]) = xru;
    }

#pragma unroll
    for (int i = 0; i < 8; ++i) {
        float a[8] = {0.f, 0.f, 0.f, 0.f, 0.f, 0.f, 0.f, 0.f};
        int lim = min(dg[i], 32);
        int nit = (lim + 7) >> 3;    // uniform: ALL lanes run each shfl
        for (int j = 0; j < nit; ++j) {
            int k = nb + j * 8;
            int s = __shfl(idxreg[i], k, 32);
            uint4 u = *reinterpret_cast<const uint4*>(&hin[s * DH + q * 8]);
            if (k < lim) {
                a[0] += bflo(u.x); a[1] += bfhi(u.x);
                a[2] += bflo(u.y); a[3] += bfhi(u.y);
                a[4] += bflo(u.z); a[5] += bfhi(u.z);
                a[6] += bflo(u.w); a[7] += bfhi(u.w);
            }
        }
        for (int k = 32 + nb; k < dg[i]; k += 8) {   // rare deg>32 tail
            int s = adj[row[i] + k];
            uint4 u = *reinterpret_cast<const uint4*>(&hin[s * DH + q * 8]);
            a[0] += bflo(u.x); a[1] += bfhi(u.x);
            a[2] += bflo(u.y); a[3] += bfhi(u.y);
            a[4] += bflo(u.z); a[5] += bfhi(u.z);
            a[6] += bflo(u.w); a[7] += bfhi(u.w);
        }
#pragma unroll
        for (int m = 0; m < 8; ++m) {
            a[m] += __shfl_xor(a[m], 4);
            a[m] += __shfl_xor(a[m], 8);
            a[m] += __shfl_xor(a[m], 16);
        }
        if (t < 4) {
            float inv = 1.0f / fmaxf((float)dg[i], 1.0f);
            uint4 mm;
            mm.x = pk2(a[0] * inv, a[1] * inv);
            mm.y = pk2(a[2] * inv, a[3] * inv);
            mm.z = pk2(a[4] * inv, a[5] * inv);
            mm.w = pk2(a[6] * inv, a[7] * inv);
            *reinterpret_cast<uint4*>(&sA[(g * 8 + i) * 72 + t * 8]) = mm;
        }
    }
}

// ============ layer 2 ============
__launch_bounds__(128)
__global__ void layer2_mfma(const bf* __restrict__ hin, const int* __restrict__ degI,
                            const int* __restrict__ start, const int* __restrict__ adj,
                            const u16* __restrict__ Bt, const float* __restrict__ blv,
                            bf* __restrict__ hout) {
    __shared__ __align__(16) short sA[32 * 72];
    int tid = threadIdx.x;
    int base = blockIdx.x * 32;

    gather32(hin, degI, start, adj, sA, base, tid);
    __syncthreads();

    int wid = tid >> 6, lane = tid & 63;
    int r16 = lane & 15, k8 = (lane >> 4) * 8;
    const short* ap = &sA[(wid * 16 + r16) * 72];
    bf16x8 av0 = *reinterpret_cast<const bf16x8*>(&ap[k8]);
    bf16x8 av1 = *reinterpret_cast<const bf16x8*>(&ap[32 + k8]);
    const u16* b0p = &Bt[r16 * 64];
    const u16* b1p = &Bt[(16 + r16) * 64];
    bf16x8 b00 = *reinterpret_cast<const bf16x8*>(&b0p[k8]);
    bf16x8 b01 = *reinterpret_cast<const bf16x8*>(&b0p[32 + k8]);
    bf16x8 b10 = *reinterpret_cast<const bf16x8*>(&b1p[k8]);
    bf16x8 b11 = *reinterpret_cast<const bf16x8*>(&b1p[32 + k8]);
    f32x4 acc0 = {0.f, 0.f, 0.f, 0.f}, acc1 = {0.f, 0.f, 0.f, 0.f};
    acc0 = __builtin_amdgcn_mfma_f32_16x16x32_bf16(av0, b00, acc0, 0, 0, 0);
    acc0 = __builtin_amdgcn_mfma_f32_16x16x32_bf16(av1, b01, acc0, 0, 0, 0);
    acc1 = __builtin_amdgcn_mfma_f32_16x16x32_bf16(av0, b10, acc1, 0, 0, 0);
    acc1 = __builtin_amdgcn_mfma_f32_16x16x32_bf16(av1, b11, acc1, 0, 0, 0);
    float bias0 = blv[r16], bias1 = blv[16 + r16];
    int rbase = base + wid * 16 + (lane >> 4) * 4;
#pragma unroll
    for (int reg = 0; reg < 4; ++reg) {
        int node = rbase + reg;
        hout[node * DH + r16]      = __float2bfloat16(fmaxf(acc0[reg] + bias0, 0.f));
        hout[node * DH + 16 + r16] = __float2bfloat16(fmaxf(acc1[reg] + bias1, 0.f));
    }
}

// ============ layer 3 + head (LDS overlaid: sA -> h3 -> hmid) ============
__launch_bounds__(128)
__global__ void layer3_mfma(const bf* __restrict__ hin, const int* __restrict__ degI,
                            const int* __restrict__ start, const int* __restrict__ adj,
                            const u16* __restrict__ B3t, const float* __restrict__ bl3,
                            const u16* __restrict__ Bh1t, const float* __restrict__ bh1,
                            const float* __restrict__ Wh2, const float* __restrict__ bh2,
                            float* __restrict__ out) {
    __shared__ __align__(16) short sA[32 * 72];
    __shared__ float sW2[NACT * DH];
    int tid = threadIdx.x;
    int base = blockIdx.x * 32;

    if (tid < NACT * DH) {
        int a = tid >> 5, k = tid & 31;
        sW2[a * DH + k] = Wh2[k * NACT + a];
    }

    gather32(hin, degI, start, adj, sA, base, tid);
    __syncthreads();

    int wid = tid >> 6, lane = tid & 63;
    int r16 = lane & 15, k8 = (lane >> 4) * 8;
    int rloc = wid * 16 + (lane >> 4) * 4;

    // stage 1: SAGE conv
    f32x4 acc0 = {0.f, 0.f, 0.f, 0.f}, acc1 = {0.f, 0.f, 0.f, 0.f};
    {
        const short* ap = &sA[(wid * 16 + r16) * 72];
        bf16x8 av0 = *reinterpret_cast<const bf16x8*>(&ap[k8]);
        bf16x8 av1 = *reinterpret_cast<const bf16x8*>(&ap[32 + k8]);
        const u16* b0p = &B3t[r16 * 64];
        const u16* b1p = &B3t[(16 + r16) * 64];
        bf16x8 b00 = *reinterpret_cast<const bf16x8*>(&b0p[k8]);
        bf16x8 b01 = *reinterpret_cast<const bf16x8*>(&b0p[32 + k8]);
        bf16x8 b10 = *reinterpret_cast<const bf16x8*>(&b1p[k8]);
        bf16x8 b11 = *reinterpret_cast<const bf16x8*>(&b1p[32 + k8]);
        acc0 = __builtin_amdgcn_mfma_f32_16x16x32_bf16(av0, b00, acc0, 0, 0, 0);
        acc0 = __builtin_amdgcn_mfma_f32_16x16x32_bf16(av1, b01, acc0, 0, 0, 0);
        acc1 = __builtin_amdgcn_mfma_f32_16x16x32_bf16(av0, b10, acc1, 0, 0, 0);
        acc1 = __builtin_amdgcn_mfma_f32_16x16x32_bf16(av1, b11, acc1, 0, 0, 0);
    }
    __syncthreads();

    bf* h3b = reinterpret_cast<bf*>(sA);   // overlay: [32][40] bf16
    {
        float bias0 = bl3[r16], bias1 = bl3[16 + r16];
#pragma unroll
        for (int reg = 0; reg < 4; ++reg) {
            int rr = rloc + reg;
            h3b[rr * 40 + r16]      = __float2bfloat16(fmaxf(acc0[reg] + bias0, 0.f));
            h3b[rr * 40 + 16 + r16] = __float2bfloat16(fmaxf(acc1[reg] + bias1, 0.f));
        }
    }
    __syncthreads();

    // stage 2: hmid = relu(h3 @ Wh1 + bh1)
    f32x4 d0 = {0.f, 0.f, 0.f, 0.f}, d1 = {0.f, 0.f, 0.f, 0.f};
    {
        bf16x8 av = *reinterpret_cast<const bf16x8*>(&h3b[(wid * 16 + r16) * 40 + k8]);
        bf16x8 b0 = *reinterpret_cast<const bf16x8*>(&Bh1t[r16 * 32 + k8]);
        bf16x8 b1 = *reinterpret_cast<const bf16x8*>(&Bh1t[(16 + r16) * 32 + k8]);
        d0 = __builtin_amdgcn_mfma_f32_16x16x32_bf16(av, b0, d0, 0, 0, 0);
        d1 = __builtin_amdgcn_mfma_f32_16x16x32_bf16(av, b1, d1, 0, 0, 0);
    }
    __syncthreads();

    float* shm = reinterpret_cast<float*>(sA);   // overlay: [32][36] f32
    {
        float hb0 = bh1[r16], hb1 = bh1[16 + r16];
#pragma unroll
        for (int reg = 0; reg < 4; ++reg) {
            int rr = rloc + reg;
            shm[rr * 36 + r16]      = fmaxf(d0[reg] + hb0, 0.f);
            shm[rr * 36 + 16 + r16] = fmaxf(d1[reg] + hb1, 0.f);
        }
    }
    __syncthreads();

    // stage 3: out = hmid @ Wh2 + bh2
    {
        int m = tid >> 2, a = tid & 3;
        if (a < NACT) {
            float o = bh2[a];
            const float* hp = &shm[m * 36];
            const float* wp = &sW2[a * DH];
#pragma unroll
            for (int k = 0; k < DH; k += 4) {
                f32x4 hv = *reinterpret_cast<const f32x4*>(&hp[k]);
                f32x4 wv = *reinterpret_cast<const f32x4*>(&wp[k]);
                o += hv.x * wv.x + hv.y * wv.y + hv.z * wv.z + hv.w * wv.w;
            }
            out[(base + m) * NACT + a] = o;
        }
    }
}

extern "C" void kernel_launch(void* const* d_in, const int* in_sizes, int n_in,
                              void* d_out, int out_size, void* d_ws, size_t ws_size,
                              hipStream_t stream) {
    const float* x   = (const float*)d_in[0];
    const int*   ei  = (const int*)d_in[1];
    const int*   src = ei;
    const int*   dst = ei + NE;
    const float* Wl1 = (const float*)d_in[2];
    const float* bl1 = (const float*)d_in[3];
    const float* Wr1 = (const float*)d_in[4];
    const float* Wl2 = (const float*)d_in[5];
    const float* bl2 = (const float*)d_in[6];
    const float* Wr2 = (const float*)d_in[7];
    const float* Wl3 = (const float*)d_in[8];
    const float* bl3 = (const float*)d_in[9];
    const float* Wr3 = (const float*)d_in[10];
    const float* Wh1 = (const float*)d_in[11];
    const float* bh1 = (const float*)d_in[12];
    const float* Wh2 = (const float*)d_in[13];
    const float* bh2 = (const float*)d_in[14];
    float* out = (float*)d_out;

    int* bucket      = (int*)d_ws;               // NBKT
    int* degI        = bucket + NBKT;            // NN
    int* startP      = degI + NN;                // NN
    int* adj         = startP + NN;              // NE
    unsigned* ebuf   = (unsigned*)(adj + NE);    // NBKT*CAPB
    u16* B1t         = (u16*)(ebuf + NBKT * CAPB); // 1024
    u16* B2t         = B1t + 1024;               // 2048
    u16* B3t         = B2t + 2048;               // 2048
    u16* Bh1t        = B3t + 2048;               // 1024
    bf*  hA          = (bf*)(Bh1t + 1024);       // DH*NN
    bf*  hB          = hA + DH * NN;             // DH*NN

    hipMemsetAsync(bucket, 0, NBKT * sizeof(int), stream);

    prep_weights<<<1, 256, 0, stream>>>(Wl1, Wr1, Wl2, Wr2, Wl3, Wr3, Wh1,
                                        B1t, B2t, B3t, Bh1t);

    // ---- build CSR: partition -> fused per-bucket base+count+scan+fill ----
    partition_edges<<<PA, 256, 0, stream>>>(src, dst, bucket, ebuf);
    fill_fused<<<NBKT, 256, 0, stream>>>(bucket, ebuf, degI, startP, adj);

    // ---- layers ----
    layer1_mfma<<<LG32, 128, 0, stream>>>(x, degI, startP, adj, B1t, bl1, hA);
    layer2_mfma<<<LG32, 128, 0, stream>>>(hA, degI, startP, adj, B2t, bl2, hB);
    layer3_mfma<<<LG32, 128, 0, stream>>>(hB, degI, startP, adj, B3t, bl3,
                                          Bh1t, bh1, Wh2, bh2, out);
}